// Round 1
// baseline (3362.238 us; speedup 1.0000x reference)
//
#include <hip/hip_runtime.h>
#include <math.h>

constexpr int nB = 64, nT = 512, nE = 768, nH = 128, nG = 512, nC = 18;
constexpr int nBT = nB * nT;

__device__ __forceinline__ float sigf(float x) { return 1.0f / (1.0f + expf(-x)); }
__device__ __forceinline__ float rlane(float v, int lane) {
  return __uint_as_float(__builtin_amdgcn_readlane(__float_as_uint(v), lane));
}

// ---------------- projection GEMM: P = X @ W^T + bias (both dirs) ----------------
__global__ __launch_bounds__(256) void proj_kernel(
    const float* __restrict__ X,
    const float* __restrict__ Wf, const float* __restrict__ bf_,
    const float* __restrict__ Wb, const float* __restrict__ bb_,
    float* __restrict__ Pf, float* __restrict__ Pb)
{
  int bid = blockIdx.x;
  const int dir = bid & 1; bid >>= 1;
  const int mt = bid >> 3;   // 512 m-tiles of 64 rows
  const int nt = bid & 7;    // 8 n-tiles of 64 cols
  const float* W = dir ? Wb : Wf;
  const float* bias = dir ? bb_ : bf_;
  float* P = dir ? Pb : Pf;

  __shared__ float As[16][68];  // As[k][m], padded
  __shared__ float Bs[16][68];  // Bs[k][n]
  const int tid = threadIdx.x;
  const int tx = tid & 15, ty = tid >> 4;
  const int lr = tid >> 2, lk = (tid & 3) << 2;
  const int m0 = mt * 64, n0 = nt * 64;
  const float* Xp = X + (size_t)(m0 + lr) * nE + lk;
  const float* Wp = W + (size_t)(n0 + lr) * nE + lk;

  float acc[4][4];
#pragma unroll
  for (int i = 0; i < 4; ++i)
#pragma unroll
    for (int j = 0; j < 4; ++j) acc[i][j] = 0.f;

  for (int k0 = 0; k0 < nE; k0 += 16) {
    const float4 av = *(const float4*)(Xp + k0);
    const float4 bv = *(const float4*)(Wp + k0);
    __syncthreads();
    As[lk + 0][lr] = av.x; As[lk + 1][lr] = av.y; As[lk + 2][lr] = av.z; As[lk + 3][lr] = av.w;
    Bs[lk + 0][lr] = bv.x; Bs[lk + 1][lr] = bv.y; Bs[lk + 2][lr] = bv.z; Bs[lk + 3][lr] = bv.w;
    __syncthreads();
#pragma unroll
    for (int k = 0; k < 16; ++k) {
      const float4 a = *(const float4*)&As[k][ty << 2];
      const float4 b = *(const float4*)&Bs[k][tx << 2];
      const float ar[4] = {a.x, a.y, a.z, a.w};
      const float br[4] = {b.x, b.y, b.z, b.w};
#pragma unroll
      for (int i = 0; i < 4; ++i)
#pragma unroll
        for (int j = 0; j < 4; ++j) acc[i][j] = fmaf(ar[i], br[j], acc[i][j]);
    }
  }
#pragma unroll
  for (int i = 0; i < 4; ++i) {
    const int row = m0 + (ty << 2) + i;
#pragma unroll
    for (int j = 0; j < 4; ++j) {
      const int col = n0 + (tx << 2) + j;
      P[(size_t)row * nG + col] = acc[i][j] + bias[col];
    }
  }
}

// ---------------- LSTM recurrence: 64 blocks = (32 batch-pairs) x (2 dirs) ----------------
// thread tid (0..255) computes gates tid and tid+256 for both batches of its pair.
// h broadcast across lanes via v_readlane (uniform index).
#define DOT4(wv, wv2, hs0, hs1, kb) do {                                   \
    float hv0 = rlane(hs0, (kb) + 0), hv1 = rlane(hs1, (kb) + 0);          \
    g0a = fmaf((wv).x, hv0, g0a); g0b = fmaf((wv2).x, hv0, g0b);           \
    g1a = fmaf((wv).x, hv1, g1a); g1b = fmaf((wv2).x, hv1, g1b);           \
    hv0 = rlane(hs0, (kb) + 1); hv1 = rlane(hs1, (kb) + 1);                \
    g0a = fmaf((wv).y, hv0, g0a); g0b = fmaf((wv2).y, hv0, g0b);           \
    g1a = fmaf((wv).y, hv1, g1a); g1b = fmaf((wv2).y, hv1, g1b);           \
    hv0 = rlane(hs0, (kb) + 2); hv1 = rlane(hs1, (kb) + 2);                \
    g0a = fmaf((wv).z, hv0, g0a); g0b = fmaf((wv2).z, hv0, g0b);           \
    g1a = fmaf((wv).z, hv1, g1a); g1b = fmaf((wv2).z, hv1, g1b);           \
    hv0 = rlane(hs0, (kb) + 3); hv1 = rlane(hs1, (kb) + 3);                \
    g0a = fmaf((wv).w, hv0, g0a); g0b = fmaf((wv2).w, hv0, g0b);           \
    g1a = fmaf((wv).w, hv1, g1a); g1b = fmaf((wv2).w, hv1, g1b);           \
  } while (0)

__global__ __launch_bounds__(256) void lstm_kernel(
    const float* __restrict__ Pf, const float* __restrict__ Pb,
    const float* __restrict__ WhhF, const float* __restrict__ WhhB,
    float* __restrict__ hf, float* __restrict__ hb)
{
  const int dir = blockIdx.x & 1;
  const int pair = blockIdx.x >> 1;
  const int b0 = pair * 2, b1 = b0 + 1;
  const float* pre = dir ? Pb : Pf;
  const float* Whh = dir ? WhhB : WhhF;
  float* hs = dir ? hb : hf;

  const int tid = threadIdx.x;
  const int lane = tid & 63;
  __shared__ float g_s[2][nG];
  __shared__ float h_s[2][nH];

  const float4* W4a = (const float4*)(Whh + (size_t)tid * nH);
  const float4* W4b = (const float4*)(Whh + (size_t)(tid + 256) * nH);

  float h0a = 0.f, h0b = 0.f, h1a = 0.f, h1b = 0.f;
  float c = 0.f;
  const int cb = tid >> 7;    // which batch of the pair this thread's cell belongs to
  const int cm = tid & 127;   // cell index

  for (int t = 0; t < nT; ++t) {
    const int ttime = dir ? (nT - 1 - t) : t;
    const float* p0 = pre + ((size_t)b0 * nT + ttime) * nG;
    const float* p1 = pre + ((size_t)b1 * nT + ttime) * nG;
    float g0a = p0[tid], g0b = p0[tid + 256];
    float g1a = p1[tid], g1b = p1[tid + 256];
#pragma unroll
    for (int q = 0; q < 16; ++q) {      // k = 0..63
      const float4 wA = W4a[q];
      const float4 wB = W4b[q];
      DOT4(wA, wB, h0a, h1a, q * 4);
    }
#pragma unroll
    for (int q = 0; q < 16; ++q) {      // k = 64..127
      const float4 wA = W4a[16 + q];
      const float4 wB = W4b[16 + q];
      DOT4(wA, wB, h0b, h1b, q * 4);
    }
    g_s[0][tid] = g0a; g_s[0][tid + 256] = g0b;
    g_s[1][tid] = g1a; g_s[1][tid + 256] = g1b;
    __syncthreads();
    {
      const float gi = g_s[cb][cm];
      const float gf = g_s[cb][nH + cm];
      const float gg = g_s[cb][2 * nH + cm];
      const float go = g_s[cb][3 * nH + cm];
      c = sigf(gf) * c + sigf(gi) * tanhf(gg);
      const float h = sigf(go) * tanhf(c);
      h_s[cb][cm] = h;
      const int bb = cb ? b1 : b0;
      hs[((size_t)bb * nT + ttime) * nH + cm] = h;
    }
    __syncthreads();
    h0a = h_s[0][lane]; h0b = h_s[0][64 + lane];
    h1a = h_s[1][lane]; h1b = h_s[1][64 + lane];
    // next iteration's g_s writes are fenced by its own __syncthreads()
  }
}

// ---------------- emissions: em = [hf|hb] @ Wfc^T + bfc ----------------
__global__ __launch_bounds__(256) void em_kernel(
    const float* __restrict__ hf, const float* __restrict__ hb,
    const float* __restrict__ Wfc, const float* __restrict__ bfc,
    float* __restrict__ em)
{
  __shared__ float seq[32][260];
  __shared__ float Wf[18][260];
  const int tid = threadIdx.x;
  const int row0 = blockIdx.x * 32;
  for (int i = tid; i < 32 * 256; i += 256) {
    const int r = i >> 8, k = i & 255;
    const size_t bt = row0 + r;
    seq[r][k] = (k < nH) ? hf[bt * nH + k] : hb[bt * nH + (k - nH)];
  }
  for (int i = tid; i < nC * 256; i += 256) {
    const int cc = i >> 8, k = i & 255;
    Wf[cc][k] = Wfc[cc * 256 + k];
  }
  __syncthreads();
  for (int o = tid; o < 32 * nC; o += 256) {
    const int r = o / nC, cc = o - r * nC;
    float acc = bfc[cc];
    const float4* s4 = (const float4*)&seq[r][0];
    const float4* w4 = (const float4*)&Wf[cc][0];
#pragma unroll
    for (int q = 0; q < 64; ++q) {
      const float4 a = s4[q]; const float4 w = w4[q];
      acc += a.x * w.x + a.y * w.y + a.z * w.z + a.w * w.w;
    }
    em[(size_t)(row0 + r) * nC + cc] = acc;
  }
}

// ---------------- CRF log-likelihood (one wave per batch) ----------------
__global__ __launch_bounds__(64) void crf_kernel(
    const float* __restrict__ em, const int* __restrict__ labels,
    const int* __restrict__ mask, const float* __restrict__ start,
    const float* __restrict__ endt, const float* __restrict__ trans,
    float* __restrict__ llh)
{
  const int b = blockIdx.x; const int l = threadIdx.x;
  __shared__ float tr[nC * nC];
  __shared__ float alpha[nC];
  for (int i = l; i < nC * nC; i += 64) tr[i] = trans[i];
  __syncthreads();
  const int* tg = labels + (size_t)b * nT;
  const int* mk = mask + (size_t)b * nT;
  const float* eb = em + (size_t)b * nT * nC;

  // numerator (strided over t, wave-reduced)
  float np = 0.f; int cnt = 0;
  for (int t = l; t < nT; t += 64) {
    const int tag = tg[t];
    const float e = eb[(size_t)t * nC + tag];
    if (t == 0) np += start[tag] + e;
    else {
      const float m = (float)mk[t];
      np += m * (e + tr[tg[t - 1] * nC + tag]);
    }
    cnt += mk[t];
  }
#pragma unroll
  for (int off = 32; off; off >>= 1) { np += __shfl_xor(np, off); cnt += __shfl_xor(cnt, off); }
  float num = np;
  const int last_idx = cnt - 1;
  num += endt[tg[last_idx]];

  // alpha recurrence
  if (l < nC) alpha[l] = start[l] + eb[l];
  float epre = (l < nC) ? eb[nC + l] : 0.f;
  __syncthreads();
  for (int t = 1; t < nT; ++t) {
    const float ecur = epre;
    if (l < nC && t + 1 < nT) epre = eb[(size_t)(t + 1) * nC + l];
    float anew = 0.f;
    if (l < nC) {
      float cand[nC];
      float m = -3.0e38f;
#pragma unroll
      for (int i = 0; i < nC; ++i) { cand[i] = alpha[i] + tr[i * nC + l]; m = fmaxf(m, cand[i]); }
      float s = 0.f;
#pragma unroll
      for (int i = 0; i < nC; ++i) s += expf(cand[i] - m);
      anew = m + logf(s) + ecur;
      if (mk[t] == 0) anew = alpha[l];
    }
    __syncthreads();
    if (l < nC) alpha[l] = anew;
    __syncthreads();
  }
  // denominator
  const float v = (l < nC) ? (alpha[l] + endt[l]) : -3.0e38f;
  float m = v;
#pragma unroll
  for (int off = 32; off; off >>= 1) m = fmaxf(m, __shfl_xor(m, off));
  float s = (l < nC) ? expf(v - m) : 0.f;
#pragma unroll
  for (int off = 32; off; off >>= 1) s += __shfl_xor(s, off);
  const float den = m + logf(s);
  if (l == 0) llh[b] = num - den;
}

// ---------------- Viterbi (one wave per batch) ----------------
__global__ __launch_bounds__(64) void viterbi_kernel(
    const float* __restrict__ em, const float* __restrict__ start,
    const float* __restrict__ endt, const float* __restrict__ trans,
    float* __restrict__ out_path)
{
  const int b = blockIdx.x; const int l = threadIdx.x;
  __shared__ float tr[nC * nC];
  __shared__ float score[nC];
  __shared__ unsigned char bp[(nT - 1) * nC];
  __shared__ unsigned char path[nT];
  for (int i = l; i < nC * nC; i += 64) tr[i] = trans[i];
  const float* eb = em + (size_t)b * nT * nC;
  if (l < nC) score[l] = start[l] + eb[l];
  float epre = (l < nC) ? eb[nC + l] : 0.f;
  __syncthreads();
  for (int t = 1; t < nT; ++t) {
    const float ecur = epre;
    if (l < nC && t + 1 < nT) epre = eb[(size_t)(t + 1) * nC + l];
    float m = -3.0e38f; int arg = 0;
    if (l < nC) {
#pragma unroll
      for (int i = 0; i < nC; ++i) {
        const float v = score[i] + tr[i * nC + l];
        if (v > m) { m = v; arg = i; }
      }
      m += ecur;
    }
    __syncthreads();
    if (l < nC) { score[l] = m; bp[(t - 1) * nC + l] = (unsigned char)arg; }
    __syncthreads();
  }
  if (l == 0) {
    float m = -3.0e38f; int last = 0;
    for (int i = 0; i < nC; ++i) { const float v = score[i] + endt[i]; if (v > m) { m = v; last = i; } }
    path[nT - 1] = (unsigned char)last;
    int cur = last;
    for (int t = nT - 2; t >= 0; --t) { cur = bp[t * nC + cur]; path[t] = (unsigned char)cur; }
  }
  __syncthreads();
  for (int t = l; t < nT; t += 64) out_path[(size_t)b * nT + t] = (float)(path[t] + 1);
}

// ---------------- loss finalize ----------------
__global__ __launch_bounds__(64) void loss_kernel(const float* __restrict__ llh, float* __restrict__ out)
{
  const int l = threadIdx.x;
  float v = llh[l];
#pragma unroll
  for (int off = 32; off; off >>= 1) v += __shfl_xor(v, off);
  if (l == 0) out[0] = -v / (float)nB;
}

extern "C" void kernel_launch(void* const* d_in, const int* in_sizes, int n_in,
                              void* d_out, int out_size, void* d_ws, size_t ws_size,
                              hipStream_t stream)
{
  const float* x      = (const float*)d_in[0];
  const int*   amask  = (const int*)d_in[1];
  const int*   labels = (const int*)d_in[2];
  const float* Wih_f  = (const float*)d_in[3];
  const float* Whh_f  = (const float*)d_in[4];
  const float* b_f    = (const float*)d_in[5];
  const float* Wih_b  = (const float*)d_in[6];
  const float* Whh_b  = (const float*)d_in[7];
  const float* b_b    = (const float*)d_in[8];
  const float* Wfc    = (const float*)d_in[9];
  const float* bfc    = (const float*)d_in[10];
  const float* start  = (const float*)d_in[11];
  const float* endt   = (const float*)d_in[12];
  const float* trans  = (const float*)d_in[13];

  float* out = (float*)d_out;
  float* ws = (float*)d_ws;
  float* preF = ws;                          // 16,777,216 f32
  float* preB = preF + (size_t)nBT * nG;     // 16,777,216
  float* hf   = preB + (size_t)nBT * nG;     // 4,194,304
  float* hb   = hf + (size_t)nBT * nH;       // 4,194,304
  float* em   = hb + (size_t)nBT * nH;       // 589,824
  float* llh  = em + (size_t)nBT * nC;       // 64

  proj_kernel<<<8192, 256, 0, stream>>>(x, Wih_f, b_f, Wih_b, b_b, preF, preB);
  lstm_kernel<<<64, 256, 0, stream>>>(preF, preB, Whh_f, Whh_b, hf, hb);
  em_kernel<<<1024, 256, 0, stream>>>(hf, hb, Wfc, bfc, em);
  crf_kernel<<<64, 64, 0, stream>>>(em, labels, amask, start, endt, trans, llh);
  viterbi_kernel<<<64, 64, 0, stream>>>(em, start, endt, trans, out);
  loss_kernel<<<1, 64, 0, stream>>>(llh, out + nBT);
}

// Round 2
// 1603.989 us; speedup vs baseline: 2.0962x; 2.0962x over previous
//
#include <hip/hip_runtime.h>
#include <hip/hip_bf16.h>
#include <math.h>

typedef __attribute__((ext_vector_type(8))) short short8;
typedef __attribute__((ext_vector_type(4))) float f32x4;

constexpr int nB = 64, nT = 512, nE = 768, nH = 128, nG = 512, nC = 18;
constexpr int nBT = nB * nT;

__device__ __forceinline__ float bf2f(unsigned short u) { return __uint_as_float(((unsigned int)u) << 16); }
__device__ __forceinline__ unsigned short f2bf(float f) {
  __hip_bfloat16 h = __float2bfloat16(f);
  return *reinterpret_cast<unsigned short*>(&h);
}
__device__ __forceinline__ float fast_sig(float x) {
  return __builtin_amdgcn_rcpf(1.0f + __builtin_amdgcn_exp2f(-1.44269504f * x));
}
__device__ __forceinline__ float fast_tanh(float x) {
  return 1.0f - 2.0f * __builtin_amdgcn_rcpf(1.0f + __builtin_amdgcn_exp2f(2.88539008f * x));
}

// ---------------- f32 -> bf16 convert ----------------
__global__ __launch_bounds__(256) void cvt_kernel(const float* __restrict__ in,
                                                  unsigned short* __restrict__ out, int n8) {
  int i = blockIdx.x * blockDim.x + threadIdx.x;
  const int stride = gridDim.x * blockDim.x;
  for (; i < n8; i += stride) {
    const float4 a = ((const float4*)in)[(size_t)i * 2];
    const float4 b = ((const float4*)in)[(size_t)i * 2 + 1];
    unsigned short u[8] = {f2bf(a.x), f2bf(a.y), f2bf(a.z), f2bf(a.w),
                           f2bf(b.x), f2bf(b.y), f2bf(b.z), f2bf(b.w)};
    ((float4*)out)[i] = *(float4*)u;
  }
}

// ---------------- projection GEMM (bf16 MFMA): pre = x @ Wih^T + b ----------------
// grid 2048: bid = sub*256 + mt, sub = dir*4+nt (A-panel sharers land on same XCD via %8)
__global__ __launch_bounds__(256) void proj_kernel(
    const unsigned short* __restrict__ xbf,
    const unsigned short* __restrict__ wfb, const unsigned short* __restrict__ wbb,
    const float* __restrict__ biasF, const float* __restrict__ biasB,
    unsigned short* __restrict__ Pf, unsigned short* __restrict__ Pb)
{
  const int bid = blockIdx.x;
  const int mt = bid & 255, sub = bid >> 8;
  const int dir = sub >> 2, nt = sub & 3;
  const unsigned short* W = dir ? wbb : wfb;
  const float* bias = dir ? biasB : biasF;
  unsigned short* P = dir ? Pb : Pf;
  const int m0 = mt * 128, n0 = nt * 128;

  __shared__ unsigned short As[128 * 40];  // [row][40], 80B rows -> conflict-free-ish b128 reads
  __shared__ unsigned short Bs[128 * 40];
  const int tid = threadIdx.x;
  const int w = tid >> 6, lane = tid & 63, l15 = lane & 15, l4 = lane >> 4;
  const int wr = w >> 1, wc = w & 1;
  const int srow = tid >> 1, shalf = tid & 1;

  const unsigned short* srcA = xbf + (size_t)(m0 + srow) * nE + shalf * 16;
  const unsigned short* srcB = W + (size_t)(n0 + srow) * nE + shalf * 16;

  f32x4 acc[4][4];
#pragma unroll
  for (int i = 0; i < 4; ++i)
#pragma unroll
    for (int j = 0; j < 4; ++j) acc[i][j] = (f32x4){0.f, 0.f, 0.f, 0.f};

  for (int k0 = 0; k0 < nE; k0 += 32) {
    const float4 a0 = *(const float4*)(srcA + k0);
    const float4 a1 = *(const float4*)(srcA + k0 + 8);
    const float4 b0 = *(const float4*)(srcB + k0);
    const float4 b1 = *(const float4*)(srcB + k0 + 8);
    __syncthreads();
    *(float4*)&As[srow * 40 + shalf * 16] = a0;
    *(float4*)&As[srow * 40 + shalf * 16 + 8] = a1;
    *(float4*)&Bs[srow * 40 + shalf * 16] = b0;
    *(float4*)&Bs[srow * 40 + shalf * 16 + 8] = b1;
    __syncthreads();
    short8 af[4], bfr[4];
#pragma unroll
    for (int i = 0; i < 4; ++i) af[i] = *(const short8*)&As[(wr * 64 + i * 16 + l15) * 40 + l4 * 8];
#pragma unroll
    for (int j = 0; j < 4; ++j) bfr[j] = *(const short8*)&Bs[(wc * 64 + j * 16 + l15) * 40 + l4 * 8];
#pragma unroll
    for (int i = 0; i < 4; ++i)
#pragma unroll
      for (int j = 0; j < 4; ++j)
        acc[i][j] = __builtin_amdgcn_mfma_f32_16x16x32_bf16(af[i], bfr[j], acc[i][j], 0, 0, 0);
  }
  float bv[4];
#pragma unroll
  for (int j = 0; j < 4; ++j) bv[j] = bias[n0 + wc * 64 + j * 16 + l15];
#pragma unroll
  for (int i = 0; i < 4; ++i) {
#pragma unroll
    for (int j = 0; j < 4; ++j) {
      const int col = n0 + wc * 64 + j * 16 + l15;
#pragma unroll
      for (int r = 0; r < 4; ++r) {
        const int row = m0 + wr * 64 + i * 16 + l4 * 4 + r;
        P[(size_t)row * nG + col] = f2bf(acc[i][j][r] + bv[j]);
      }
    }
  }
}

// ---------------- MFMA LSTM: 8 blocks = 4 groups x 2 dirs, 16 batches/block ----------------
__global__ __launch_bounds__(256, 1) void lstm_kernel(
    const unsigned short* __restrict__ Pf, const unsigned short* __restrict__ Pb,
    const float* __restrict__ WhhF, const float* __restrict__ WhhB,
    unsigned short* __restrict__ hf, unsigned short* __restrict__ hb)
{
  const int bid = blockIdx.x;
  const int dir = bid & 1, grp = bid >> 1;
  const int b0 = grp * 16;
  const unsigned short* pre = dir ? Pb : Pf;
  const float* Whh = dir ? WhhB : WhhF;
  unsigned short* hout = dir ? hb : hf;

  const int tid = threadIdx.x, w = tid >> 6, lane = tid & 63, l15 = lane & 15, l4 = lane >> 4;

  __shared__ unsigned short h_lds[16 * 128];  // XOR-swizzled: idx = row*128 + (cell ^ ((row&7)<<3))

  // Whh as MFMA B-fragments in registers, wave w owns cells [w*32, w*32+32)
  short8 Bf[8][4];
#pragma unroll
  for (int f = 0; f < 8; ++f) {
    const int g = (f >> 1) * 128 + w * 32 + (f & 1) * 16 + l15;
#pragma unroll
    for (int kk = 0; kk < 4; ++kk) {
      const float* wp = Whh + (size_t)g * nH + kk * 32 + l4 * 8;
      const float4 v0 = *(const float4*)wp;
      const float4 v1 = *(const float4*)(wp + 4);
      unsigned short u[8] = {f2bf(v0.x), f2bf(v0.y), f2bf(v0.z), f2bf(v0.w),
                             f2bf(v1.x), f2bf(v1.y), f2bf(v1.z), f2bf(v1.w)};
      Bf[f][kk] = *(short8*)u;
    }
  }
  for (int i = tid; i < 16 * 128; i += 256) h_lds[i] = 0;

  float c_state[8];
#pragma unroll
  for (int i = 0; i < 8; ++i) c_state[i] = 0.f;

  // prefetch pre for first timestep
  unsigned int preN[32];
  {
    const int tt0 = dir ? (nT - 1) : 0;
#pragma unroll
    for (int f = 0; f < 8; ++f) {
      const int gcol = (f >> 1) * 128 + w * 32 + (f & 1) * 16 + l15;
#pragma unroll
      for (int r = 0; r < 4; ++r)
        preN[f * 4 + r] = pre[((size_t)(b0 + l4 * 4 + r) * nT + tt0) * nG + gcol];
    }
  }
  __syncthreads();

  for (int t = 0; t < nT; ++t) {
    const int ttime = dir ? (nT - 1 - t) : t;
    // A fragments (prev h) from LDS
    short8 af[4];
#pragma unroll
    for (int kk = 0; kk < 4; ++kk) {
      const int idx = l15 * 128 + ((kk * 32 + l4 * 8) ^ ((l15 & 7) << 3));
      af[kk] = *(const short8*)&h_lds[idx];
    }
    // acc init from prefetched pre, then issue next-t prefetch
    f32x4 acc[8];
#pragma unroll
    for (int f = 0; f < 8; ++f)
#pragma unroll
      for (int r = 0; r < 4; ++r) acc[f][r] = bf2f((unsigned short)preN[f * 4 + r]);
    if (t + 1 < nT) {
      const int tn = dir ? (nT - 2 - t) : (t + 1);
#pragma unroll
      for (int f = 0; f < 8; ++f) {
        const int gcol = (f >> 1) * 128 + w * 32 + (f & 1) * 16 + l15;
#pragma unroll
        for (int r = 0; r < 4; ++r)
          preN[f * 4 + r] = pre[((size_t)(b0 + l4 * 4 + r) * nT + tn) * nG + gcol];
      }
    }
    __syncthreads();  // all h_lds reads done before any wave overwrites below

#pragma unroll
    for (int kk = 0; kk < 4; ++kk)
#pragma unroll
      for (int f = 0; f < 8; ++f)
        acc[f] = __builtin_amdgcn_mfma_f32_16x16x32_bf16(af[kk], Bf[f][kk], acc[f], 0, 0, 0);

    // activations: this lane owns 8 (batch,cell) states
    unsigned short hu[8];
#pragma unroll
    for (int cs = 0; cs < 2; ++cs)
#pragma unroll
      for (int r = 0; r < 4; ++r) {
        const float gi = acc[0 * 2 + cs][r];
        const float gf = acc[1 * 2 + cs][r];
        const float gg = acc[2 * 2 + cs][r];
        const float go = acc[3 * 2 + cs][r];
        float c = fast_sig(gf) * c_state[cs * 4 + r] + fast_sig(gi) * fast_tanh(gg);
        c_state[cs * 4 + r] = c;
        hu[cs * 4 + r] = f2bf(fast_sig(go) * fast_tanh(c));
      }
#pragma unroll
    for (int cs = 0; cs < 2; ++cs)
#pragma unroll
      for (int r = 0; r < 4; ++r) {
        const int row = l4 * 4 + r;
        const int cell = w * 32 + cs * 16 + l15;
        h_lds[row * 128 + (cell ^ ((row & 7) << 3))] = hu[cs * 4 + r];
        hout[((size_t)(b0 + row) * nT + ttime) * nH + cell] = hu[cs * 4 + r];
      }
    __syncthreads();
  }
}

// ---------------- emissions: em = [hf|hb] @ Wfc^T + bfc (h is bf16) ----------------
__global__ __launch_bounds__(256) void em_kernel(
    const unsigned short* __restrict__ hf, const unsigned short* __restrict__ hb,
    const float* __restrict__ Wfc, const float* __restrict__ bfc,
    float* __restrict__ em)
{
  __shared__ float seq[32][260];
  __shared__ float Wf[18][260];
  const int tid = threadIdx.x;
  const int row0 = blockIdx.x * 32;
  for (int i = tid; i < 32 * 32; i += 256) {
    const int r = i >> 5, seg = i & 31;
    const unsigned short* src = (seg < 16) ? (hf + (size_t)(row0 + r) * nH + seg * 8)
                                           : (hb + (size_t)(row0 + r) * nH + (seg - 16) * 8);
    const float4 v = *(const float4*)src;
    const unsigned short* u = (const unsigned short*)&v;
#pragma unroll
    for (int k = 0; k < 8; ++k) seq[r][seg * 8 + k] = bf2f(u[k]);
  }
  for (int i = tid; i < nC * 256; i += 256) {
    const int cc = i >> 8, k = i & 255;
    Wf[cc][k] = Wfc[cc * 256 + k];
  }
  __syncthreads();
  for (int o = tid; o < 32 * nC; o += 256) {
    const int r = o / nC, cc = o - r * nC;
    float acc = bfc[cc];
    const float4* s4 = (const float4*)&seq[r][0];
    const float4* w4 = (const float4*)&Wf[cc][0];
#pragma unroll
    for (int q = 0; q < 64; ++q) {
      const float4 a = s4[q]; const float4 wv = w4[q];
      acc += a.x * wv.x + a.y * wv.y + a.z * wv.z + a.w * wv.w;
    }
    em[(size_t)(row0 + r) * nC + cc] = acc;
  }
}

// ---------------- CRF log-likelihood (one wave per batch) ----------------
__global__ __launch_bounds__(64) void crf_kernel(
    const float* __restrict__ em, const int* __restrict__ labels,
    const int* __restrict__ mask, const float* __restrict__ start,
    const float* __restrict__ endt, const float* __restrict__ trans,
    float* __restrict__ llh)
{
  const int b = blockIdx.x; const int l = threadIdx.x;
  __shared__ float tr[nC * nC];
  __shared__ float alpha[nC];
  for (int i = l; i < nC * nC; i += 64) tr[i] = trans[i];
  __syncthreads();
  const int* tg = labels + (size_t)b * nT;
  const int* mk = mask + (size_t)b * nT;
  const float* eb = em + (size_t)b * nT * nC;

  float np = 0.f; int cnt = 0;
  for (int t = l; t < nT; t += 64) {
    const int tag = tg[t];
    const float e = eb[(size_t)t * nC + tag];
    if (t == 0) np += start[tag] + e;
    else {
      const float m = (float)mk[t];
      np += m * (e + tr[tg[t - 1] * nC + tag]);
    }
    cnt += mk[t];
  }
#pragma unroll
  for (int off = 32; off; off >>= 1) { np += __shfl_xor(np, off); cnt += __shfl_xor(cnt, off); }
  float num = np;
  const int last_idx = cnt - 1;
  num += endt[tg[last_idx]];

  if (l < nC) alpha[l] = start[l] + eb[l];
  float epre = (l < nC) ? eb[nC + l] : 0.f;
  __syncthreads();
  for (int t = 1; t < nT; ++t) {
    const float ecur = epre;
    if (l < nC && t + 1 < nT) epre = eb[(size_t)(t + 1) * nC + l];
    float anew = 0.f;
    if (l < nC) {
      float cand[nC];
      float m = -3.0e38f;
#pragma unroll
      for (int i = 0; i < nC; ++i) { cand[i] = alpha[i] + tr[i * nC + l]; m = fmaxf(m, cand[i]); }
      float s = 0.f;
#pragma unroll
      for (int i = 0; i < nC; ++i) s += expf(cand[i] - m);
      anew = m + logf(s) + ecur;
      if (mk[t] == 0) anew = alpha[l];
    }
    __syncthreads();
    if (l < nC) alpha[l] = anew;
    __syncthreads();
  }
  const float v = (l < nC) ? (alpha[l] + endt[l]) : -3.0e38f;
  float m = v;
#pragma unroll
  for (int off = 32; off; off >>= 1) m = fmaxf(m, __shfl_xor(m, off));
  float s = (l < nC) ? expf(v - m) : 0.f;
#pragma unroll
  for (int off = 32; off; off >>= 1) s += __shfl_xor(s, off);
  const float den = m + logf(s);
  if (l == 0) llh[b] = num - den;
}

// ---------------- Viterbi (one wave per batch) ----------------
__global__ __launch_bounds__(64) void viterbi_kernel(
    const float* __restrict__ em, const float* __restrict__ start,
    const float* __restrict__ endt, const float* __restrict__ trans,
    float* __restrict__ out_path)
{
  const int b = blockIdx.x; const int l = threadIdx.x;
  __shared__ float tr[nC * nC];
  __shared__ float score[nC];
  __shared__ unsigned char bp[(nT - 1) * nC];
  __shared__ unsigned char path[nT];
  for (int i = l; i < nC * nC; i += 64) tr[i] = trans[i];
  const float* eb = em + (size_t)b * nT * nC;
  if (l < nC) score[l] = start[l] + eb[l];
  float epre = (l < nC) ? eb[nC + l] : 0.f;
  __syncthreads();
  for (int t = 1; t < nT; ++t) {
    const float ecur = epre;
    if (l < nC && t + 1 < nT) epre = eb[(size_t)(t + 1) * nC + l];
    float m = -3.0e38f; int arg = 0;
    if (l < nC) {
#pragma unroll
      for (int i = 0; i < nC; ++i) {
        const float v = score[i] + tr[i * nC + l];
        if (v > m) { m = v; arg = i; }
      }
      m += ecur;
    }
    __syncthreads();
    if (l < nC) { score[l] = m; bp[(t - 1) * nC + l] = (unsigned char)arg; }
    __syncthreads();
  }
  if (l == 0) {
    float m = -3.0e38f; int last = 0;
    for (int i = 0; i < nC; ++i) { const float v = score[i] + endt[i]; if (v > m) { m = v; last = i; } }
    path[nT - 1] = (unsigned char)last;
    int cur = last;
    for (int t = nT - 2; t >= 0; --t) { cur = bp[t * nC + cur]; path[t] = (unsigned char)cur; }
  }
  __syncthreads();
  for (int t = l; t < nT; t += 64) out_path[(size_t)b * nT + t] = (float)(path[t] + 1);
}

// ---------------- loss finalize ----------------
__global__ __launch_bounds__(64) void loss_kernel(const float* __restrict__ llh, float* __restrict__ out)
{
  const int l = threadIdx.x;
  float v = llh[l];
#pragma unroll
  for (int off = 32; off; off >>= 1) v += __shfl_xor(v, off);
  if (l == 0) out[0] = -v / (float)nB;
}

extern "C" void kernel_launch(void* const* d_in, const int* in_sizes, int n_in,
                              void* d_out, int out_size, void* d_ws, size_t ws_size,
                              hipStream_t stream)
{
  const float* x      = (const float*)d_in[0];
  const int*   amask  = (const int*)d_in[1];
  const int*   labels = (const int*)d_in[2];
  const float* Wih_f  = (const float*)d_in[3];
  const float* Whh_f  = (const float*)d_in[4];
  const float* b_f    = (const float*)d_in[5];
  const float* Wih_b  = (const float*)d_in[6];
  const float* Whh_b  = (const float*)d_in[7];
  const float* b_b    = (const float*)d_in[8];
  const float* Wfc    = (const float*)d_in[9];
  const float* bfc    = (const float*)d_in[10];
  const float* start  = (const float*)d_in[11];
  const float* endt   = (const float*)d_in[12];
  const float* trans  = (const float*)d_in[13];

  float* out = (float*)d_out;
  float* ws = (float*)d_ws;
  // layout in f32 units
  unsigned short* preF = (unsigned short*)ws;                       // 16,777,216 bf16
  unsigned short* preB = preF + (size_t)nBT * nG;                   // 16,777,216 bf16
  unsigned short* hf   = preB + (size_t)nBT * nG;                   // 4,194,304 bf16
  unsigned short* hb   = hf + (size_t)nBT * nH;                     // 4,194,304 bf16
  float* em  = (float*)(hb + (size_t)nBT * nH);                     // 589,824 f32
  float* llh = em + (size_t)nBT * nC;                               // 64 f32
  unsigned short* xbf = (unsigned short*)(llh + 64);                // 25,165,824 bf16
  unsigned short* wfb = xbf + (size_t)nBT * nE;                     // 393,216 bf16
  unsigned short* wbb = wfb + (size_t)nG * nE;                      // 393,216 bf16

  cvt_kernel<<<4096, 256, 0, stream>>>(x, xbf, nBT * nE / 8);
  cvt_kernel<<<192, 256, 0, stream>>>(Wih_f, wfb, nG * nE / 8);
  cvt_kernel<<<192, 256, 0, stream>>>(Wih_b, wbb, nG * nE / 8);
  proj_kernel<<<2048, 256, 0, stream>>>(xbf, wfb, wbb, b_f, b_b, preF, preB);
  lstm_kernel<<<8, 256, 0, stream>>>(preF, preB, Whh_f, Whh_b, hf, hb);
  em_kernel<<<1024, 256, 0, stream>>>(hf, hb, Wfc, bfc, em);
  crf_kernel<<<64, 64, 0, stream>>>(em, labels, amask, start, endt, trans, llh);
  viterbi_kernel<<<64, 64, 0, stream>>>(em, start, endt, trans, out);
  loss_kernel<<<1, 64, 0, stream>>>(llh, out + nBT);
}

// Round 3
// 1082.864 us; speedup vs baseline: 3.1049x; 1.4812x over previous
//
#include <hip/hip_runtime.h>
#include <hip/hip_bf16.h>
#include <math.h>

typedef __attribute__((ext_vector_type(8))) short short8;
typedef __attribute__((ext_vector_type(4))) float f32x4;

constexpr int nB = 64, nT = 512, nE = 768, nH = 128, nG = 512, nC = 18;
constexpr int nBT = nB * nT;

__device__ __forceinline__ float bf2f(unsigned short u) { return __uint_as_float(((unsigned int)u) << 16); }
__device__ __forceinline__ unsigned short f2bf(float f) {
  __hip_bfloat16 h = __float2bfloat16(f);
  return *reinterpret_cast<unsigned short*>(&h);
}
__device__ __forceinline__ float fast_sig(float x) {
  return __builtin_amdgcn_rcpf(1.0f + __builtin_amdgcn_exp2f(-1.44269504f * x));
}
__device__ __forceinline__ float fast_tanh(float x) {
  return 1.0f - 2.0f * __builtin_amdgcn_rcpf(1.0f + __builtin_amdgcn_exp2f(2.88539008f * x));
}
__device__ __forceinline__ float fast_exp(float x) { return __builtin_amdgcn_exp2f(1.44269504f * x); }
__device__ __forceinline__ float fast_log(float x) { return __builtin_amdgcn_logf(x) * 0.69314718f; }

// ---------------- f32 -> bf16 convert ----------------
__global__ __launch_bounds__(256) void cvt_kernel(const float* __restrict__ in,
                                                  unsigned short* __restrict__ out, int n8) {
  int i = blockIdx.x * blockDim.x + threadIdx.x;
  const int stride = gridDim.x * blockDim.x;
  for (; i < n8; i += stride) {
    const float4 a = ((const float4*)in)[(size_t)i * 2];
    const float4 b = ((const float4*)in)[(size_t)i * 2 + 1];
    unsigned short u[8] = {f2bf(a.x), f2bf(a.y), f2bf(a.z), f2bf(a.w),
                           f2bf(b.x), f2bf(b.y), f2bf(b.z), f2bf(b.w)};
    ((float4*)out)[i] = *(float4*)u;
  }
}

// ---------------- projection GEMM (bf16 MFMA): pre = x @ Wih^T + b ----------------
__global__ __launch_bounds__(256) void proj_kernel(
    const unsigned short* __restrict__ xbf,
    const unsigned short* __restrict__ wfb, const unsigned short* __restrict__ wbb,
    const float* __restrict__ biasF, const float* __restrict__ biasB,
    unsigned short* __restrict__ Pf, unsigned short* __restrict__ Pb)
{
  const int bid = blockIdx.x;
  const int mt = bid & 255, sub = bid >> 8;
  const int dir = sub >> 2, nt = sub & 3;
  const unsigned short* W = dir ? wbb : wfb;
  const float* bias = dir ? biasB : biasF;
  unsigned short* P = dir ? Pb : Pf;
  const int m0 = mt * 128, n0 = nt * 128;

  __shared__ unsigned short As[128 * 40];
  __shared__ unsigned short Bs[128 * 40];
  const int tid = threadIdx.x;
  const int w = tid >> 6, lane = tid & 63, l15 = lane & 15, l4 = lane >> 4;
  const int wr = w >> 1, wc = w & 1;
  const int srow = tid >> 1, shalf = tid & 1;

  const unsigned short* srcA = xbf + (size_t)(m0 + srow) * nE + shalf * 16;
  const unsigned short* srcB = W + (size_t)(n0 + srow) * nE + shalf * 16;

  f32x4 acc[4][4];
#pragma unroll
  for (int i = 0; i < 4; ++i)
#pragma unroll
    for (int j = 0; j < 4; ++j) acc[i][j] = (f32x4){0.f, 0.f, 0.f, 0.f};

  for (int k0 = 0; k0 < nE; k0 += 32) {
    const float4 a0 = *(const float4*)(srcA + k0);
    const float4 a1 = *(const float4*)(srcA + k0 + 8);
    const float4 b0 = *(const float4*)(srcB + k0);
    const float4 b1 = *(const float4*)(srcB + k0 + 8);
    __syncthreads();
    *(float4*)&As[srow * 40 + shalf * 16] = a0;
    *(float4*)&As[srow * 40 + shalf * 16 + 8] = a1;
    *(float4*)&Bs[srow * 40 + shalf * 16] = b0;
    *(float4*)&Bs[srow * 40 + shalf * 16 + 8] = b1;
    __syncthreads();
    short8 af[4], bfr[4];
#pragma unroll
    for (int i = 0; i < 4; ++i) af[i] = *(const short8*)&As[(wr * 64 + i * 16 + l15) * 40 + l4 * 8];
#pragma unroll
    for (int j = 0; j < 4; ++j) bfr[j] = *(const short8*)&Bs[(wc * 64 + j * 16 + l15) * 40 + l4 * 8];
#pragma unroll
    for (int i = 0; i < 4; ++i)
#pragma unroll
      for (int j = 0; j < 4; ++j)
        acc[i][j] = __builtin_amdgcn_mfma_f32_16x16x32_bf16(af[i], bfr[j], acc[i][j], 0, 0, 0);
  }
  float bv[4];
#pragma unroll
  for (int j = 0; j < 4; ++j) bv[j] = bias[n0 + wc * 64 + j * 16 + l15];
#pragma unroll
  for (int i = 0; i < 4; ++i) {
#pragma unroll
    for (int j = 0; j < 4; ++j) {
      const int col = n0 + wc * 64 + j * 16 + l15;
#pragma unroll
      for (int r = 0; r < 4; ++r) {
        const int row = m0 + wr * 64 + i * 16 + l4 * 4 + r;
        P[(size_t)row * nG + col] = f2bf(acc[i][j][r] + bv[j]);
      }
    }
  }
}

// ---------------- MFMA LSTM v3: 32 blocks = 16 groups x 2 dirs, 4 batches/block ----------------
// Gate-major: A = Whh rows permuted so gate' = cell*4 + gatetype (register fragments),
// B = h^T from swizzled LDS. acc f32x4 = (i,f,g,o) of one cell -> LDS redistribution
// gives 1 cell per thread for activations (10 trans ops/lane/t).
__global__ __launch_bounds__(512) void lstm_kernel(
    const unsigned short* __restrict__ Pf, const unsigned short* __restrict__ Pb,
    const float* __restrict__ WhhF, const float* __restrict__ WhhB,
    unsigned short* __restrict__ hf, unsigned short* __restrict__ hb)
{
  const int bid = blockIdx.x;
  const int dir = bid & 1, grp = bid >> 1;
  const int b0 = grp * 4;
  const unsigned short* pre = dir ? Pb : Pf;
  const float* Whh = dir ? WhhB : WhhF;
  unsigned short* hout = dir ? hb : hf;

  const int tid = threadIdx.x, w = tid >> 6, lane = tid & 63;
  const int l15 = lane & 15, l4 = lane >> 4;

  __shared__ unsigned short h_lds[2][16 * 128];  // XOR-swizzled, double-buffered
  __shared__ float gates_lds[4 * 516];           // [batch][gate'], stride 516 kills write conflicts

  // A fragments: Whh_perm rows w*64+m*16+l15, k = kk*32+l4*8
  short8 Af[4][4];
#pragma unroll
  for (int m = 0; m < 4; ++m) {
    const int gp = w * 64 + m * 16 + l15;
    const int gorig = (gp & 3) * 128 + (gp >> 2);
#pragma unroll
    for (int kk = 0; kk < 4; ++kk) {
      const float* wp = Whh + (size_t)gorig * nH + kk * 32 + l4 * 8;
      const float4 v0 = *(const float4*)wp;
      const float4 v1 = *(const float4*)(wp + 4);
      unsigned short u[8] = {f2bf(v0.x), f2bf(v0.y), f2bf(v0.z), f2bf(v0.w),
                             f2bf(v1.x), f2bf(v1.y), f2bf(v1.z), f2bf(v1.w)};
      Af[m][kk] = *(short8*)u;
    }
  }
  for (int i = tid; i < 2 * 16 * 128; i += 512) ((unsigned short*)h_lds)[i] = 0;

  const int ab = tid >> 7, ac = tid & 127;  // activation thread -> (batch, cell)
  float c_state = 0.f;

  unsigned short preC[16], preN[16];
  const int bl = l15 & 3;
  {
    const int tt0 = dir ? (nT - 1) : 0;
#pragma unroll
    for (int m = 0; m < 4; ++m)
#pragma unroll
      for (int r = 0; r < 4; ++r)
        preC[m * 4 + r] = pre[((size_t)(b0 + bl) * nT + tt0) * nG + r * 128 + w * 16 + m * 4 + l4];
  }
  __syncthreads();

  for (int t = 0; t < nT; ++t) {
    const int ttime = dir ? (nT - 1 - t) : t;
    const int rb = t & 1, wb = rb ^ 1;
    short8 bfr[4];
#pragma unroll
    for (int kk = 0; kk < 4; ++kk) {
      const int idx = l15 * 128 + ((kk * 32 + l4 * 8) ^ ((l15 & 7) << 3));
      bfr[kk] = *(const short8*)&h_lds[rb][idx];
    }
    f32x4 acc[4];
#pragma unroll
    for (int m = 0; m < 4; ++m)
#pragma unroll
      for (int r = 0; r < 4; ++r) acc[m][r] = bf2f(preC[m * 4 + r]);
    if (t + 1 < nT) {
      const int tn = dir ? (nT - 2 - t) : (t + 1);
#pragma unroll
      for (int m = 0; m < 4; ++m)
#pragma unroll
        for (int r = 0; r < 4; ++r)
          preN[m * 4 + r] = pre[((size_t)(b0 + bl) * nT + tn) * nG + r * 128 + w * 16 + m * 4 + l4];
    }
#pragma unroll
    for (int kk = 0; kk < 4; ++kk)
#pragma unroll
      for (int m = 0; m < 4; ++m)
        acc[m] = __builtin_amdgcn_mfma_f32_16x16x32_bf16(Af[m][kk], bfr[kk], acc[m], 0, 0, 0);
    if (l15 < 4) {
#pragma unroll
      for (int m = 0; m < 4; ++m)
        *(f32x4*)&gates_lds[l15 * 516 + w * 64 + m * 16 + l4 * 4] = acc[m];
    }
    __syncthreads();
    {
      const float4 g4 = *(const float4*)&gates_lds[ab * 516 + ac * 4];  // (i,f,g,o)
      c_state = fast_sig(g4.y) * c_state + fast_sig(g4.x) * fast_tanh(g4.z);
      const float h = fast_sig(g4.w) * fast_tanh(c_state);
      const unsigned short hu = f2bf(h);
      h_lds[wb][ab * 128 + (ac ^ (ab << 3))] = hu;
      hout[((size_t)(b0 + ab) * nT + ttime) * nH + ac] = hu;
    }
#pragma unroll
    for (int i = 0; i < 16; ++i) preC[i] = preN[i];
    __syncthreads();
  }
}

// ---------------- emissions: em = [hf|hb] @ Wfc^T + bfc ----------------
__global__ __launch_bounds__(256) void em_kernel(
    const unsigned short* __restrict__ hf, const unsigned short* __restrict__ hb,
    const float* __restrict__ Wfc, const float* __restrict__ bfc,
    float* __restrict__ em)
{
  __shared__ float seq[32][260];
  __shared__ float Wf[18][260];
  const int tid = threadIdx.x;
  const int row0 = blockIdx.x * 32;
  for (int i = tid; i < 32 * 32; i += 256) {
    const int r = i >> 5, seg = i & 31;
    const unsigned short* src = (seg < 16) ? (hf + (size_t)(row0 + r) * nH + seg * 8)
                                           : (hb + (size_t)(row0 + r) * nH + (seg - 16) * 8);
    const float4 v = *(const float4*)src;
    const unsigned short* u = (const unsigned short*)&v;
#pragma unroll
    for (int k = 0; k < 8; ++k) seq[r][seg * 8 + k] = bf2f(u[k]);
  }
  for (int i = tid; i < nC * 256; i += 256) {
    const int cc = i >> 8, k = i & 255;
    Wf[cc][k] = Wfc[cc * 256 + k];
  }
  __syncthreads();
  for (int o = tid; o < 32 * nC; o += 256) {
    const int r = o / nC, cc = o - r * nC;
    float acc = bfc[cc];
    const float4* s4 = (const float4*)&seq[r][0];
    const float4* w4 = (const float4*)&Wf[cc][0];
#pragma unroll
    for (int q = 0; q < 64; ++q) {
      const float4 a = s4[q]; const float4 wv = w4[q];
      acc += a.x * wv.x + a.y * wv.y + a.z * wv.z + a.w * wv.w;
    }
    em[(size_t)(row0 + r) * nC + cc] = acc;
  }
}

// ---------------- fused CRF + Viterbi: 64 blocks x 2 waves, barrier-free loops ----------------
__global__ __launch_bounds__(128) void crfvit_kernel(
    const float* __restrict__ em, const int* __restrict__ labels,
    const int* __restrict__ mask, const float* __restrict__ start,
    const float* __restrict__ endt, const float* __restrict__ trans,
    float* __restrict__ llh, float* __restrict__ out_path)
{
  const int b = blockIdx.x; const int tid = threadIdx.x;
  __shared__ float tr[nC * nC];
  __shared__ float alpha[nC];
  __shared__ float score[nC];
  __shared__ unsigned char bp[(nT - 1) * nC];
  __shared__ unsigned char path[nT];
  for (int i = tid; i < nC * nC; i += 128) tr[i] = trans[i];
  __syncthreads();
  const float* eb = em + (size_t)b * nT * nC;

  if (tid < 64) {
    // ------- CRF wave -------
    const int l = tid;
    const int* tg = labels + (size_t)b * nT;
    const int* mk = mask + (size_t)b * nT;
    float np = 0.f; int cnt = 0;
    for (int t = l; t < nT; t += 64) {
      const int tag = tg[t];
      const float e = eb[(size_t)t * nC + tag];
      if (t == 0) np += start[tag] + e;
      else np += (float)mk[t] * (e + tr[tg[t - 1] * nC + tag]);
      cnt += mk[t];
    }
#pragma unroll
    for (int off = 32; off; off >>= 1) { np += __shfl_xor(np, off); cnt += __shfl_xor(cnt, off); }
    float num = np + endt[tg[cnt - 1]];

    if (l < nC) alpha[l] = start[l] + eb[l];
    float epre = (l < nC) ? eb[nC + l] : 0.f;
    __builtin_amdgcn_wave_barrier();
    for (int t = 1; t < nT; ++t) {
      const float ecur = epre;
      if (l < nC && t + 1 < nT) epre = eb[(size_t)(t + 1) * nC + l];
      float anew = 0.f;
      if (l < nC) {
        const float aold = alpha[l];
        float cand[nC];
        float m = -3.0e38f;
#pragma unroll
        for (int i = 0; i < nC; ++i) { cand[i] = alpha[i] + tr[i * nC + l]; m = fmaxf(m, cand[i]); }
        float s = 0.f;
#pragma unroll
        for (int i = 0; i < nC; ++i) s += fast_exp(cand[i] - m);
        anew = m + fast_log(s) + ecur;
        if (mk[t] == 0) anew = aold;
      }
      __builtin_amdgcn_wave_barrier();
      if (l < nC) alpha[l] = anew;
      __builtin_amdgcn_wave_barrier();
    }
    const float v = (l < nC) ? (alpha[l] + endt[l]) : -3.0e38f;
    float m = v;
#pragma unroll
    for (int off = 32; off; off >>= 1) m = fmaxf(m, __shfl_xor(m, off));
    float s = (l < nC) ? fast_exp(v - m) : 0.f;
#pragma unroll
    for (int off = 32; off; off >>= 1) s += __shfl_xor(s, off);
    if (l == 0) llh[b] = num - (m + fast_log(s));
  } else {
    // ------- Viterbi wave -------
    const int l = tid - 64;
    if (l < nC) score[l] = start[l] + eb[l];
    float epre = (l < nC) ? eb[nC + l] : 0.f;
    __builtin_amdgcn_wave_barrier();
    for (int t = 1; t < nT; ++t) {
      const float ecur = epre;
      if (l < nC && t + 1 < nT) epre = eb[(size_t)(t + 1) * nC + l];
      float m = -3.0e38f; int arg = 0;
      if (l < nC) {
#pragma unroll
        for (int i = 0; i < nC; ++i) {
          const float v = score[i] + tr[i * nC + l];
          if (v > m) { m = v; arg = i; }
        }
        m += ecur;
      }
      __builtin_amdgcn_wave_barrier();
      if (l < nC) { score[l] = m; bp[(t - 1) * nC + l] = (unsigned char)arg; }
      __builtin_amdgcn_wave_barrier();
    }
    if (l == 0) {
      float m = -3.0e38f; int last = 0;
      for (int i = 0; i < nC; ++i) { const float v = score[i] + endt[i]; if (v > m) { m = v; last = i; } }
      path[nT - 1] = (unsigned char)last;
      int cur = last;
      for (int t = nT - 2; t >= 0; --t) { cur = bp[t * nC + cur]; path[t] = (unsigned char)cur; }
    }
    __builtin_amdgcn_wave_barrier();
    __builtin_amdgcn_s_waitcnt(0);  // ensure path writes visible (same wave: program order suffices)
    for (int t = l; t < nT; t += 64) out_path[(size_t)b * nT + t] = (float)(path[t] + 1);
  }
}

// ---------------- loss finalize ----------------
__global__ __launch_bounds__(64) void loss_kernel(const float* __restrict__ llh, float* __restrict__ out)
{
  const int l = threadIdx.x;
  float v = llh[l];
#pragma unroll
  for (int off = 32; off; off >>= 1) v += __shfl_xor(v, off);
  if (l == 0) out[0] = -v / (float)nB;
}

extern "C" void kernel_launch(void* const* d_in, const int* in_sizes, int n_in,
                              void* d_out, int out_size, void* d_ws, size_t ws_size,
                              hipStream_t stream)
{
  const float* x      = (const float*)d_in[0];
  const int*   amask  = (const int*)d_in[1];
  const int*   labels = (const int*)d_in[2];
  const float* Wih_f  = (const float*)d_in[3];
  const float* Whh_f  = (const float*)d_in[4];
  const float* b_f    = (const float*)d_in[5];
  const float* Wih_b  = (const float*)d_in[6];
  const float* Whh_b  = (const float*)d_in[7];
  const float* b_b    = (const float*)d_in[8];
  const float* Wfc    = (const float*)d_in[9];
  const float* bfc    = (const float*)d_in[10];
  const float* start  = (const float*)d_in[11];
  const float* endt   = (const float*)d_in[12];
  const float* trans  = (const float*)d_in[13];

  float* out = (float*)d_out;
  float* ws = (float*)d_ws;
  unsigned short* preF = (unsigned short*)ws;                       // 16.7M bf16
  unsigned short* preB = preF + (size_t)nBT * nG;                   // 16.7M bf16
  unsigned short* hf   = preB + (size_t)nBT * nG;                   // 4.2M bf16
  unsigned short* hb   = hf + (size_t)nBT * nH;                     // 4.2M bf16
  float* em  = (float*)(hb + (size_t)nBT * nH);                     // 590K f32
  float* llh = em + (size_t)nBT * nC;                               // 64 f32
  unsigned short* xbf = (unsigned short*)(llh + 64);                // 25.2M bf16
  unsigned short* wfb = xbf + (size_t)nBT * nE;                     // 393K bf16
  unsigned short* wbb = wfb + (size_t)nG * nE;                      // 393K bf16

  cvt_kernel<<<4096, 256, 0, stream>>>(x, xbf, nBT * nE / 8);
  cvt_kernel<<<192, 256, 0, stream>>>(Wih_f, wfb, nG * nE / 8);
  cvt_kernel<<<192, 256, 0, stream>>>(Wih_b, wbb, nG * nE / 8);
  proj_kernel<<<2048, 256, 0, stream>>>(xbf, wfb, wbb, b_f, b_b, preF, preB);
  lstm_kernel<<<32, 512, 0, stream>>>(preF, preB, Whh_f, Whh_b, hf, hb);
  em_kernel<<<1024, 256, 0, stream>>>(hf, hb, Wfc, bfc, em);
  crfvit_kernel<<<64, 128, 0, stream>>>(em, labels, amask, start, endt, trans, llh, out);
  loss_kernel<<<1, 64, 0, stream>>>(llh, out + nBT);
}

// Round 4
// 630.022 us; speedup vs baseline: 5.3367x; 1.7188x over previous
//
#include <hip/hip_runtime.h>
#include <hip/hip_bf16.h>
#include <math.h>

typedef __attribute__((ext_vector_type(8))) short short8;
typedef __attribute__((ext_vector_type(4))) float f32x4;

constexpr int nB = 64, nT = 512, nE = 768, nH = 128, nG = 512, nC = 18;
constexpr int nBT = nB * nT;

__device__ __forceinline__ float bf2f(unsigned short u) { return __uint_as_float(((unsigned int)u) << 16); }
__device__ __forceinline__ unsigned short f2bf(float f) {
  __hip_bfloat16 h = __float2bfloat16(f);
  return *reinterpret_cast<unsigned short*>(&h);
}
__device__ __forceinline__ float fast_sig(float x) {
  return __builtin_amdgcn_rcpf(1.0f + __builtin_amdgcn_exp2f(-1.44269504f * x));
}
__device__ __forceinline__ float fast_tanh(float x) {
  return 1.0f - 2.0f * __builtin_amdgcn_rcpf(1.0f + __builtin_amdgcn_exp2f(2.88539008f * x));
}
__device__ __forceinline__ float fast_exp(float x) { return __builtin_amdgcn_exp2f(1.44269504f * x); }
__device__ __forceinline__ float fast_log(float x) { return __builtin_amdgcn_logf(x) * 0.69314718f; }

// ---------------- f32 -> bf16 convert ----------------
__global__ __launch_bounds__(256) void cvt_kernel(const float* __restrict__ in,
                                                  unsigned short* __restrict__ out, int n8) {
  int i = blockIdx.x * blockDim.x + threadIdx.x;
  const int stride = gridDim.x * blockDim.x;
  for (; i < n8; i += stride) {
    const float4 a = ((const float4*)in)[(size_t)i * 2];
    const float4 b = ((const float4*)in)[(size_t)i * 2 + 1];
    unsigned short u[8] = {f2bf(a.x), f2bf(a.y), f2bf(a.z), f2bf(a.w),
                           f2bf(b.x), f2bf(b.y), f2bf(b.z), f2bf(b.w)};
    ((float4*)out)[i] = *(float4*)u;
  }
}

// ---------------- projection GEMM (bf16 MFMA): pre = x @ Wih^T + b ----------------
__global__ __launch_bounds__(256) void proj_kernel(
    const unsigned short* __restrict__ xbf,
    const unsigned short* __restrict__ wfb, const unsigned short* __restrict__ wbb,
    const float* __restrict__ biasF, const float* __restrict__ biasB,
    unsigned short* __restrict__ Pf, unsigned short* __restrict__ Pb)
{
  const int bid = blockIdx.x;
  const int mt = bid & 255, sub = bid >> 8;
  const int dir = sub >> 2, nt = sub & 3;
  const unsigned short* W = dir ? wbb : wfb;
  const float* bias = dir ? biasB : biasF;
  unsigned short* P = dir ? Pb : Pf;
  const int m0 = mt * 128, n0 = nt * 128;

  __shared__ unsigned short As[128 * 40];
  __shared__ unsigned short Bs[128 * 40];
  const int tid = threadIdx.x;
  const int w = tid >> 6, lane = tid & 63, l15 = lane & 15, l4 = lane >> 4;
  const int wr = w >> 1, wc = w & 1;
  const int srow = tid >> 1, shalf = tid & 1;

  const unsigned short* srcA = xbf + (size_t)(m0 + srow) * nE + shalf * 16;
  const unsigned short* srcB = W + (size_t)(n0 + srow) * nE + shalf * 16;

  f32x4 acc[4][4];
#pragma unroll
  for (int i = 0; i < 4; ++i)
#pragma unroll
    for (int j = 0; j < 4; ++j) acc[i][j] = (f32x4){0.f, 0.f, 0.f, 0.f};

  for (int k0 = 0; k0 < nE; k0 += 32) {
    const float4 a0 = *(const float4*)(srcA + k0);
    const float4 a1 = *(const float4*)(srcA + k0 + 8);
    const float4 b0 = *(const float4*)(srcB + k0);
    const float4 b1 = *(const float4*)(srcB + k0 + 8);
    __syncthreads();
    *(float4*)&As[srow * 40 + shalf * 16] = a0;
    *(float4*)&As[srow * 40 + shalf * 16 + 8] = a1;
    *(float4*)&Bs[srow * 40 + shalf * 16] = b0;
    *(float4*)&Bs[srow * 40 + shalf * 16 + 8] = b1;
    __syncthreads();
    short8 af[4], bfr[4];
#pragma unroll
    for (int i = 0; i < 4; ++i) af[i] = *(const short8*)&As[(wr * 64 + i * 16 + l15) * 40 + l4 * 8];
#pragma unroll
    for (int j = 0; j < 4; ++j) bfr[j] = *(const short8*)&Bs[(wc * 64 + j * 16 + l15) * 40 + l4 * 8];
#pragma unroll
    for (int i = 0; i < 4; ++i)
#pragma unroll
      for (int j = 0; j < 4; ++j)
        acc[i][j] = __builtin_amdgcn_mfma_f32_16x16x32_bf16(af[i], bfr[j], acc[i][j], 0, 0, 0);
  }
  float bv[4];
#pragma unroll
  for (int j = 0; j < 4; ++j) bv[j] = bias[n0 + wc * 64 + j * 16 + l15];
#pragma unroll
  for (int i = 0; i < 4; ++i) {
#pragma unroll
    for (int j = 0; j < 4; ++j) {
      const int col = n0 + wc * 64 + j * 16 + l15;
#pragma unroll
      for (int r = 0; r < 4; ++r) {
        const int row = m0 + wr * 64 + i * 16 + l4 * 4 + r;
        P[(size_t)row * nG + col] = f2bf(acc[i][j][r] + bv[j]);
      }
    }
  }
}

// ---------------- MFMA LSTM v4: register-local gates, raw barriers, depth-2 prefetch ----
// 32 blocks = 16 groups x 2 dirs, 4 batches/block, 8 waves.
// Gate permutation gate' = cell*4 + type with type = C-row&3: lane (l15,l4) of wave w
// gets (i,f,g,o) of cell = w*16 + (l15>>2)*4 + l4, batch = l15&3 in acc[l15>>2][0..3].
// All 64 lanes handle distinct (cell,batch) -> 1 cell of activations per lane.
// Raw s_barrier (no vmcnt drain) keeps depth-2 pre-prefetch loads in flight.
__global__ __launch_bounds__(512, 1) void lstm_kernel(
    const unsigned short* __restrict__ Pf, const unsigned short* __restrict__ Pb,
    const float* __restrict__ WhhF, const float* __restrict__ WhhB,
    unsigned short* __restrict__ hf, unsigned short* __restrict__ hb)
{
  const int bid = blockIdx.x;
  const int dir = bid & 1, grp = bid >> 1;
  const int b0 = grp * 4;
  const unsigned short* pre = dir ? Pb : Pf;
  const float* Whh = dir ? WhhB : WhhF;
  unsigned short* hout = dir ? hb : hf;

  const int tid = threadIdx.x, w = tid >> 6, lane = tid & 63;
  const int l15 = lane & 15, l4 = lane >> 4;
  const int batch = l15 & 3, msel = l15 >> 2;
  const int cell = w * 16 + msel * 4 + l4;
  const int swz = batch * 40;  // XOR on bits 3-6: banks 2-way max on b128 reads

  __shared__ unsigned short h_lds[2 * 4 * 128];  // [buf][batch][cell^swz]

  // Whh -> A fragments, rows permuted: gate' = w*64 + m*16 + l15
  short8 Af[4][4];
#pragma unroll
  for (int m = 0; m < 4; ++m) {
    const int gp = w * 64 + m * 16 + l15;
    const int gorig = (gp & 3) * 128 + (gp >> 2);
#pragma unroll
    for (int kk = 0; kk < 4; ++kk) {
      const float* wp = Whh + (size_t)gorig * nH + kk * 32 + l4 * 8;
      const float4 v0 = *(const float4*)wp;
      const float4 v1 = *(const float4*)(wp + 4);
      unsigned short u[8] = {f2bf(v0.x), f2bf(v0.y), f2bf(v0.z), f2bf(v0.w),
                             f2bf(v1.x), f2bf(v1.y), f2bf(v1.z), f2bf(v1.w)};
      Af[m][kk] = *(short8*)u;
    }
  }
  for (int i = tid; i < 2 * 4 * 128; i += 512) h_lds[i] = 0;

  float c_state = 0.f;
  // this lane's 4 gate pre-activations live at pbase + ttime*nG + r*128
  const unsigned short* pbase = pre + (size_t)(b0 + batch) * nT * nG + cell;

  unsigned short pA[4], pB[4];
  {
    const int tt0 = dir ? (nT - 1) : 0;
    const int tt1 = dir ? (nT - 2) : 1;
#pragma unroll
    for (int r = 0; r < 4; ++r) pA[r] = pbase[(size_t)tt0 * nG + r * 128];
#pragma unroll
    for (int r = 0; r < 4; ++r) pB[r] = pbase[(size_t)tt1 * nG + r * 128];
  }
  __syncthreads();

#define LSTM_STEP(RB, T, BUFC)                                                   \
  {                                                                              \
    const int ttime = dir ? (nT - 1 - (T)) : (T);                                \
    float pg[4];                                                                 \
    _Pragma("unroll")                                                            \
    for (int r = 0; r < 4; ++r) pg[r] = bf2f(BUFC[r]);                           \
    {                                                                            \
      const int tl = ((T) + 2 < nT) ? (T) + 2 : (T);                             \
      const int ttl = dir ? (nT - 1 - tl) : tl;                                  \
      _Pragma("unroll")                                                          \
      for (int r = 0; r < 4; ++r) BUFC[r] = pbase[(size_t)ttl * nG + r * 128];   \
    }                                                                            \
    short8 bfr[4];                                                               \
    _Pragma("unroll")                                                            \
    for (int kk = 0; kk < 4; ++kk) {                                             \
      const int idx = (RB) * 512 + batch * 128 + ((kk * 32 + l4 * 8) ^ swz);     \
      bfr[kk] = *(const short8*)&h_lds[idx];                                     \
    }                                                                            \
    f32x4 acc[4];                                                                \
    _Pragma("unroll")                                                            \
    for (int m = 0; m < 4; ++m) acc[m] = (f32x4){0.f, 0.f, 0.f, 0.f};            \
    _Pragma("unroll")                                                            \
    for (int kk = 0; kk < 4; ++kk)                                               \
      _Pragma("unroll")                                                          \
      for (int m = 0; m < 4; ++m)                                                \
        acc[m] = __builtin_amdgcn_mfma_f32_16x16x32_bf16(Af[m][kk], bfr[kk], acc[m], 0, 0, 0); \
    const float g0 = msel < 2 ? (msel == 0 ? acc[0][0] : acc[1][0]) : (msel == 2 ? acc[2][0] : acc[3][0]); \
    const float g1 = msel < 2 ? (msel == 0 ? acc[0][1] : acc[1][1]) : (msel == 2 ? acc[2][1] : acc[3][1]); \
    const float g2 = msel < 2 ? (msel == 0 ? acc[0][2] : acc[1][2]) : (msel == 2 ? acc[2][2] : acc[3][2]); \
    const float g3 = msel < 2 ? (msel == 0 ? acc[0][3] : acc[1][3]) : (msel == 2 ? acc[2][3] : acc[3][3]); \
    const float gi = g0 + pg[0], gf = g1 + pg[1], gg = g2 + pg[2], go = g3 + pg[3]; \
    c_state = fast_sig(gf) * c_state + fast_sig(gi) * fast_tanh(gg);             \
    const float hval = fast_sig(go) * fast_tanh(c_state);                        \
    const unsigned short hu = f2bf(hval);                                        \
    h_lds[((RB) ^ 1) * 512 + batch * 128 + (cell ^ swz)] = hu;                   \
    hout[((size_t)(b0 + batch) * nT + ttime) * nH + cell] = hu;                  \
    asm volatile("s_waitcnt lgkmcnt(0)" ::: "memory");                           \
    __builtin_amdgcn_sched_barrier(0);                                           \
    __builtin_amdgcn_s_barrier();                                                \
  }

  for (int t2 = 0; t2 < nT; t2 += 2) {
    LSTM_STEP(0, t2, pA)
    LSTM_STEP(1, t2 + 1, pB)
  }
#undef LSTM_STEP
}

// ---------------- emissions: em = [hf|hb] @ Wfc^T + bfc ----------------
__global__ __launch_bounds__(256) void em_kernel(
    const unsigned short* __restrict__ hf, const unsigned short* __restrict__ hb,
    const float* __restrict__ Wfc, const float* __restrict__ bfc,
    float* __restrict__ em)
{
  __shared__ float seq[32][260];
  __shared__ float Wf[18][260];
  const int tid = threadIdx.x;
  const int row0 = blockIdx.x * 32;
  for (int i = tid; i < 32 * 32; i += 256) {
    const int r = i >> 5, seg = i & 31;
    const unsigned short* src = (seg < 16) ? (hf + (size_t)(row0 + r) * nH + seg * 8)
                                           : (hb + (size_t)(row0 + r) * nH + (seg - 16) * 8);
    const float4 v = *(const float4*)src;
    const unsigned short* u = (const unsigned short*)&v;
#pragma unroll
    for (int k = 0; k < 8; ++k) seq[r][seg * 8 + k] = bf2f(u[k]);
  }
  for (int i = tid; i < nC * 256; i += 256) {
    const int cc = i >> 8, k = i & 255;
    Wf[cc][k] = Wfc[cc * 256 + k];
  }
  __syncthreads();
  for (int o = tid; o < 32 * nC; o += 256) {
    const int r = o / nC, cc = o - r * nC;
    float acc = bfc[cc];
    const float4* s4 = (const float4*)&seq[r][0];
    const float4* w4 = (const float4*)&Wf[cc][0];
#pragma unroll
    for (int q = 0; q < 64; ++q) {
      const float4 a = s4[q]; const float4 wv = w4[q];
      acc += a.x * wv.x + a.y * wv.y + a.z * wv.z + a.w * wv.w;
    }
    em[(size_t)(row0 + r) * nC + cc] = acc;
  }
}

// ---------------- fused CRF + Viterbi: 64 blocks x 2 waves, barrier-free loops ----------------
__global__ __launch_bounds__(128) void crfvit_kernel(
    const float* __restrict__ em, const int* __restrict__ labels,
    const int* __restrict__ mask, const float* __restrict__ start,
    const float* __restrict__ endt, const float* __restrict__ trans,
    float* __restrict__ llh, float* __restrict__ out_path)
{
  const int b = blockIdx.x; const int tid = threadIdx.x;
  __shared__ float tr[nC * nC];
  __shared__ float alpha[nC];
  __shared__ float score[nC];
  __shared__ unsigned char bp[(nT - 1) * nC];
  __shared__ unsigned char path[nT];
  for (int i = tid; i < nC * nC; i += 128) tr[i] = trans[i];
  __syncthreads();
  const float* eb = em + (size_t)b * nT * nC;

  if (tid < 64) {
    // ------- CRF wave -------
    const int l = tid;
    const int* tg = labels + (size_t)b * nT;
    const int* mk = mask + (size_t)b * nT;
    float np = 0.f; int cnt = 0;
    for (int t = l; t < nT; t += 64) {
      const int tag = tg[t];
      const float e = eb[(size_t)t * nC + tag];
      if (t == 0) np += start[tag] + e;
      else np += (float)mk[t] * (e + tr[tg[t - 1] * nC + tag]);
      cnt += mk[t];
    }
#pragma unroll
    for (int off = 32; off; off >>= 1) { np += __shfl_xor(np, off); cnt += __shfl_xor(cnt, off); }
    float num = np + endt[tg[cnt - 1]];

    if (l < nC) alpha[l] = start[l] + eb[l];
    float epre = (l < nC) ? eb[nC + l] : 0.f;
    __builtin_amdgcn_wave_barrier();
    for (int t = 1; t < nT; ++t) {
      const float ecur = epre;
      if (l < nC && t + 1 < nT) epre = eb[(size_t)(t + 1) * nC + l];
      float anew = 0.f;
      if (l < nC) {
        const float aold = alpha[l];
        float cand[nC];
        float m = -3.0e38f;
#pragma unroll
        for (int i = 0; i < nC; ++i) { cand[i] = alpha[i] + tr[i * nC + l]; m = fmaxf(m, cand[i]); }
        float s = 0.f;
#pragma unroll
        for (int i = 0; i < nC; ++i) s += fast_exp(cand[i] - m);
        anew = m + fast_log(s) + ecur;
        if (mk[t] == 0) anew = aold;
      }
      __builtin_amdgcn_wave_barrier();
      if (l < nC) alpha[l] = anew;
      __builtin_amdgcn_wave_barrier();
    }
    const float v = (l < nC) ? (alpha[l] + endt[l]) : -3.0e38f;
    float m = v;
#pragma unroll
    for (int off = 32; off; off >>= 1) m = fmaxf(m, __shfl_xor(m, off));
    float s = (l < nC) ? fast_exp(v - m) : 0.f;
#pragma unroll
    for (int off = 32; off; off >>= 1) s += __shfl_xor(s, off);
    if (l == 0) llh[b] = num - (m + fast_log(s));
  } else {
    // ------- Viterbi wave -------
    const int l = tid - 64;
    if (l < nC) score[l] = start[l] + eb[l];
    float epre = (l < nC) ? eb[nC + l] : 0.f;
    __builtin_amdgcn_wave_barrier();
    for (int t = 1; t < nT; ++t) {
      const float ecur = epre;
      if (l < nC && t + 1 < nT) epre = eb[(size_t)(t + 1) * nC + l];
      float m = -3.0e38f; int arg = 0;
      if (l < nC) {
#pragma unroll
        for (int i = 0; i < nC; ++i) {
          const float v = score[i] + tr[i * nC + l];
          if (v > m) { m = v; arg = i; }
        }
        m += ecur;
      }
      __builtin_amdgcn_wave_barrier();
      if (l < nC) { score[l] = m; bp[(t - 1) * nC + l] = (unsigned char)arg; }
      __builtin_amdgcn_wave_barrier();
    }
    if (l == 0) {
      float m = -3.0e38f; int last = 0;
      for (int i = 0; i < nC; ++i) { const float v = score[i] + endt[i]; if (v > m) { m = v; last = i; } }
      path[nT - 1] = (unsigned char)last;
      int cur = last;
      for (int t = nT - 2; t >= 0; --t) { cur = bp[t * nC + cur]; path[t] = (unsigned char)cur; }
    }
    __builtin_amdgcn_wave_barrier();
    __builtin_amdgcn_s_waitcnt(0);
    for (int t = l; t < nT; t += 64) out_path[(size_t)b * nT + t] = (float)(path[t] + 1);
  }
}

// ---------------- loss finalize ----------------
__global__ __launch_bounds__(64) void loss_kernel(const float* __restrict__ llh, float* __restrict__ out)
{
  const int l = threadIdx.x;
  float v = llh[l];
#pragma unroll
  for (int off = 32; off; off >>= 1) v += __shfl_xor(v, off);
  if (l == 0) out[0] = -v / (float)nB;
}

extern "C" void kernel_launch(void* const* d_in, const int* in_sizes, int n_in,
                              void* d_out, int out_size, void* d_ws, size_t ws_size,
                              hipStream_t stream)
{
  const float* x      = (const float*)d_in[0];
  const int*   amask  = (const int*)d_in[1];
  const int*   labels = (const int*)d_in[2];
  const float* Wih_f  = (const float*)d_in[3];
  const float* Whh_f  = (const float*)d_in[4];
  const float* b_f    = (const float*)d_in[5];
  const float* Wih_b  = (const float*)d_in[6];
  const float* Whh_b  = (const float*)d_in[7];
  const float* b_b    = (const float*)d_in[8];
  const float* Wfc    = (const float*)d_in[9];
  const float* bfc    = (const float*)d_in[10];
  const float* start  = (const float*)d_in[11];
  const float* endt   = (const float*)d_in[12];
  const float* trans  = (const float*)d_in[13];

  float* out = (float*)d_out;
  float* ws = (float*)d_ws;
  unsigned short* preF = (unsigned short*)ws;                       // 16.7M bf16
  unsigned short* preB = preF + (size_t)nBT * nG;                   // 16.7M bf16
  unsigned short* hf   = preB + (size_t)nBT * nG;                   // 4.2M bf16
  unsigned short* hb   = hf + (size_t)nBT * nH;                     // 4.2M bf16
  float* em  = (float*)(hb + (size_t)nBT * nH);                     // 590K f32
  float* llh = em + (size_t)nBT * nC;                               // 64 f32
  unsigned short* xbf = (unsigned short*)(llh + 64);                // 25.2M bf16
  unsigned short* wfb = xbf + (size_t)nBT * nE;                     // 393K bf16
  unsigned short* wbb = wfb + (size_t)nG * nE;                      // 393K bf16

  cvt_kernel<<<4096, 256, 0, stream>>>(x, xbf, nBT * nE / 8);
  cvt_kernel<<<192, 256, 0, stream>>>(Wih_f, wfb, nG * nE / 8);
  cvt_kernel<<<192, 256, 0, stream>>>(Wih_b, wbb, nG * nE / 8);
  proj_kernel<<<2048, 256, 0, stream>>>(xbf, wfb, wbb, b_f, b_b, preF, preB);
  lstm_kernel<<<32, 512, 0, stream>>>(preF, preB, Whh_f, Whh_b, hf, hb);
  em_kernel<<<1024, 256, 0, stream>>>(hf, hb, Wfc, bfc, em);
  crfvit_kernel<<<64, 128, 0, stream>>>(em, labels, amask, start, endt, trans, llh, out);
  loss_kernel<<<1, 64, 0, stream>>>(llh, out + nBT);
}

// Round 5
// 549.046 us; speedup vs baseline: 6.1238x; 1.1475x over previous
//
#include <hip/hip_runtime.h>
#include <hip/hip_bf16.h>
#include <math.h>

typedef __attribute__((ext_vector_type(8))) short short8;
typedef __attribute__((ext_vector_type(4))) float f32x4;

constexpr int nB = 64, nT = 512, nE = 768, nH = 128, nG = 512, nC = 18;
constexpr int nBT = nB * nT;

__device__ __forceinline__ float bf2f(unsigned short u) { return __uint_as_float(((unsigned int)u) << 16); }
__device__ __forceinline__ unsigned short f2bf(float f) {
  __hip_bfloat16 h = __float2bfloat16(f);
  return *reinterpret_cast<unsigned short*>(&h);
}
__device__ __forceinline__ float rlane(float v, int lane) {
  return __uint_as_float(__builtin_amdgcn_readlane(__float_as_uint(v), lane));
}
__device__ __forceinline__ float fast_sig(float x) {
  return __builtin_amdgcn_rcpf(1.0f + __builtin_amdgcn_exp2f(-1.44269504f * x));
}
__device__ __forceinline__ float fast_tanh(float x) {
  return 1.0f - 2.0f * __builtin_amdgcn_rcpf(1.0f + __builtin_amdgcn_exp2f(2.88539008f * x));
}
__device__ __forceinline__ float fast_exp(float x) { return __builtin_amdgcn_exp2f(1.44269504f * x); }
__device__ __forceinline__ float fast_log(float x) { return __builtin_amdgcn_logf(x) * 0.69314718f; }

// ---------------- f32 -> bf16 convert (weights only) ----------------
__global__ __launch_bounds__(256) void cvt_kernel(const float* __restrict__ in,
                                                  unsigned short* __restrict__ out, int n8) {
  int i = blockIdx.x * blockDim.x + threadIdx.x;
  const int stride = gridDim.x * blockDim.x;
  for (; i < n8; i += stride) {
    const float4 a = ((const float4*)in)[(size_t)i * 2];
    const float4 b = ((const float4*)in)[(size_t)i * 2 + 1];
    unsigned short u[8] = {f2bf(a.x), f2bf(a.y), f2bf(a.z), f2bf(a.w),
                           f2bf(b.x), f2bf(b.y), f2bf(b.z), f2bf(b.w)};
    ((float4*)out)[i] = *(float4*)u;
  }
}

// ---------------- projection GEMM (bf16 MFMA): pre = x @ Wih^T + b ----------------
// A (x) read as f32 and converted during LDS staging (cvt pass fused away).
__global__ __launch_bounds__(256) void proj_kernel(
    const float* __restrict__ x,
    const unsigned short* __restrict__ wfb, const unsigned short* __restrict__ wbb,
    const float* __restrict__ biasF, const float* __restrict__ biasB,
    unsigned short* __restrict__ Pf, unsigned short* __restrict__ Pb)
{
  const int bid = blockIdx.x;
  const int mt = bid & 255, sub = bid >> 8;
  const int dir = sub >> 2, nt = sub & 3;
  const unsigned short* W = dir ? wbb : wfb;
  const float* bias = dir ? biasB : biasF;
  unsigned short* P = dir ? Pb : Pf;
  const int m0 = mt * 128, n0 = nt * 128;

  __shared__ unsigned short As[128 * 40];
  __shared__ unsigned short Bs[128 * 40];
  const int tid = threadIdx.x;
  const int w = tid >> 6, lane = tid & 63, l15 = lane & 15, l4 = lane >> 4;
  const int wr = w >> 1, wc = w & 1;
  const int srow = tid >> 1, shalf = tid & 1;

  const float* srcA = x + (size_t)(m0 + srow) * nE + shalf * 16;
  const unsigned short* srcB = W + (size_t)(n0 + srow) * nE + shalf * 16;

  f32x4 acc[4][4];
#pragma unroll
  for (int i = 0; i < 4; ++i)
#pragma unroll
    for (int j = 0; j < 4; ++j) acc[i][j] = (f32x4){0.f, 0.f, 0.f, 0.f};

  for (int k0 = 0; k0 < nE; k0 += 32) {
    const float4 a0 = *(const float4*)(srcA + k0);
    const float4 a1 = *(const float4*)(srcA + k0 + 4);
    const float4 a2 = *(const float4*)(srcA + k0 + 8);
    const float4 a3 = *(const float4*)(srcA + k0 + 12);
    const float4 b0 = *(const float4*)(srcB + k0);
    const float4 b1 = *(const float4*)(srcB + k0 + 8);
    unsigned short ua[16] = {f2bf(a0.x), f2bf(a0.y), f2bf(a0.z), f2bf(a0.w),
                             f2bf(a1.x), f2bf(a1.y), f2bf(a1.z), f2bf(a1.w),
                             f2bf(a2.x), f2bf(a2.y), f2bf(a2.z), f2bf(a2.w),
                             f2bf(a3.x), f2bf(a3.y), f2bf(a3.z), f2bf(a3.w)};
    __syncthreads();
    *(float4*)&As[srow * 40 + shalf * 16] = *(float4*)&ua[0];
    *(float4*)&As[srow * 40 + shalf * 16 + 8] = *(float4*)&ua[8];
    *(float4*)&Bs[srow * 40 + shalf * 16] = b0;
    *(float4*)&Bs[srow * 40 + shalf * 16 + 8] = b1;
    __syncthreads();
    short8 af[4], bfr[4];
#pragma unroll
    for (int i = 0; i < 4; ++i) af[i] = *(const short8*)&As[(wr * 64 + i * 16 + l15) * 40 + l4 * 8];
#pragma unroll
    for (int j = 0; j < 4; ++j) bfr[j] = *(const short8*)&Bs[(wc * 64 + j * 16 + l15) * 40 + l4 * 8];
#pragma unroll
    for (int i = 0; i < 4; ++i)
#pragma unroll
      for (int j = 0; j < 4; ++j)
        acc[i][j] = __builtin_amdgcn_mfma_f32_16x16x32_bf16(af[i], bfr[j], acc[i][j], 0, 0, 0);
  }
  float bv[4];
#pragma unroll
  for (int j = 0; j < 4; ++j) bv[j] = bias[n0 + wc * 64 + j * 16 + l15];
#pragma unroll
  for (int i = 0; i < 4; ++i) {
#pragma unroll
    for (int j = 0; j < 4; ++j) {
      const int col = n0 + wc * 64 + j * 16 + l15;
#pragma unroll
      for (int r = 0; r < 4; ++r) {
        const int row = m0 + wr * 64 + i * 16 + l4 * 4 + r;
        P[(size_t)row * nG + col] = f2bf(acc[i][j][r] + bv[j]);
      }
    }
  }
}

// ---------------- MFMA LSTM v4 (unchanged from R4) ----------------
__global__ __launch_bounds__(512, 1) void lstm_kernel(
    const unsigned short* __restrict__ Pf, const unsigned short* __restrict__ Pb,
    const float* __restrict__ WhhF, const float* __restrict__ WhhB,
    unsigned short* __restrict__ hf, unsigned short* __restrict__ hb)
{
  const int bid = blockIdx.x;
  const int dir = bid & 1, grp = bid >> 1;
  const int b0 = grp * 4;
  const unsigned short* pre = dir ? Pb : Pf;
  const float* Whh = dir ? WhhB : WhhF;
  unsigned short* hout = dir ? hb : hf;

  const int tid = threadIdx.x, w = tid >> 6, lane = tid & 63;
  const int l15 = lane & 15, l4 = lane >> 4;
  const int batch = l15 & 3, msel = l15 >> 2;
  const int cell = w * 16 + msel * 4 + l4;
  const int swz = batch * 40;

  __shared__ unsigned short h_lds[2 * 4 * 128];

  short8 Af[4][4];
#pragma unroll
  for (int m = 0; m < 4; ++m) {
    const int gp = w * 64 + m * 16 + l15;
    const int gorig = (gp & 3) * 128 + (gp >> 2);
#pragma unroll
    for (int kk = 0; kk < 4; ++kk) {
      const float* wp = Whh + (size_t)gorig * nH + kk * 32 + l4 * 8;
      const float4 v0 = *(const float4*)wp;
      const float4 v1 = *(const float4*)(wp + 4);
      unsigned short u[8] = {f2bf(v0.x), f2bf(v0.y), f2bf(v0.z), f2bf(v0.w),
                             f2bf(v1.x), f2bf(v1.y), f2bf(v1.z), f2bf(v1.w)};
      Af[m][kk] = *(short8*)u;
    }
  }
  for (int i = tid; i < 2 * 4 * 128; i += 512) h_lds[i] = 0;

  float c_state = 0.f;
  const unsigned short* pbase = pre + (size_t)(b0 + batch) * nT * nG + cell;

  unsigned short pA[4], pB[4];
  {
    const int tt0 = dir ? (nT - 1) : 0;
    const int tt1 = dir ? (nT - 2) : 1;
#pragma unroll
    for (int r = 0; r < 4; ++r) pA[r] = pbase[(size_t)tt0 * nG + r * 128];
#pragma unroll
    for (int r = 0; r < 4; ++r) pB[r] = pbase[(size_t)tt1 * nG + r * 128];
  }
  __syncthreads();

#define LSTM_STEP(RB, T, BUFC)                                                   \
  {                                                                              \
    const int ttime = dir ? (nT - 1 - (T)) : (T);                                \
    float pg[4];                                                                 \
    _Pragma("unroll")                                                            \
    for (int r = 0; r < 4; ++r) pg[r] = bf2f(BUFC[r]);                           \
    {                                                                            \
      const int tl = ((T) + 2 < nT) ? (T) + 2 : (T);                             \
      const int ttl = dir ? (nT - 1 - tl) : tl;                                  \
      _Pragma("unroll")                                                          \
      for (int r = 0; r < 4; ++r) BUFC[r] = pbase[(size_t)ttl * nG + r * 128];   \
    }                                                                            \
    short8 bfr[4];                                                               \
    _Pragma("unroll")                                                            \
    for (int kk = 0; kk < 4; ++kk) {                                             \
      const int idx = (RB) * 512 + batch * 128 + ((kk * 32 + l4 * 8) ^ swz);     \
      bfr[kk] = *(const short8*)&h_lds[idx];                                     \
    }                                                                            \
    f32x4 acc[4];                                                                \
    _Pragma("unroll")                                                            \
    for (int m = 0; m < 4; ++m) acc[m] = (f32x4){0.f, 0.f, 0.f, 0.f};            \
    _Pragma("unroll")                                                            \
    for (int kk = 0; kk < 4; ++kk)                                               \
      _Pragma("unroll")                                                          \
      for (int m = 0; m < 4; ++m)                                                \
        acc[m] = __builtin_amdgcn_mfma_f32_16x16x32_bf16(Af[m][kk], bfr[kk], acc[m], 0, 0, 0); \
    const float g0 = msel < 2 ? (msel == 0 ? acc[0][0] : acc[1][0]) : (msel == 2 ? acc[2][0] : acc[3][0]); \
    const float g1 = msel < 2 ? (msel == 0 ? acc[0][1] : acc[1][1]) : (msel == 2 ? acc[2][1] : acc[3][1]); \
    const float g2 = msel < 2 ? (msel == 0 ? acc[0][2] : acc[1][2]) : (msel == 2 ? acc[2][2] : acc[3][2]); \
    const float g3 = msel < 2 ? (msel == 0 ? acc[0][3] : acc[1][3]) : (msel == 2 ? acc[2][3] : acc[3][3]); \
    const float gi = g0 + pg[0], gf = g1 + pg[1], gg = g2 + pg[2], go = g3 + pg[3]; \
    c_state = fast_sig(gf) * c_state + fast_sig(gi) * fast_tanh(gg);             \
    const float hval = fast_sig(go) * fast_tanh(c_state);                        \
    const unsigned short hu = f2bf(hval);                                        \
    h_lds[((RB) ^ 1) * 512 + batch * 128 + (cell ^ swz)] = hu;                   \
    hout[((size_t)(b0 + batch) * nT + ttime) * nH + cell] = hu;                  \
    asm volatile("s_waitcnt lgkmcnt(0)" ::: "memory");                           \
    __builtin_amdgcn_sched_barrier(0);                                           \
    __builtin_amdgcn_s_barrier();                                                \
  }

  for (int t2 = 0; t2 < nT; t2 += 2) {
    LSTM_STEP(0, t2, pA)
    LSTM_STEP(1, t2 + 1, pB)
  }
#undef LSTM_STEP
}

// ---------------- emissions: em = [hf|hb] @ Wfc^T + bfc ----------------
__global__ __launch_bounds__(256) void em_kernel(
    const unsigned short* __restrict__ hf, const unsigned short* __restrict__ hb,
    const float* __restrict__ Wfc, const float* __restrict__ bfc,
    float* __restrict__ em)
{
  __shared__ float seq[32][260];
  __shared__ float Wf[18][260];
  const int tid = threadIdx.x;
  const int row0 = blockIdx.x * 32;
  for (int i = tid; i < 32 * 32; i += 256) {
    const int r = i >> 5, seg = i & 31;
    const unsigned short* src = (seg < 16) ? (hf + (size_t)(row0 + r) * nH + seg * 8)
                                           : (hb + (size_t)(row0 + r) * nH + (seg - 16) * 8);
    const float4 v = *(const float4*)src;
    const unsigned short* u = (const unsigned short*)&v;
#pragma unroll
    for (int k = 0; k < 8; ++k) seq[r][seg * 8 + k] = bf2f(u[k]);
  }
  for (int i = tid; i < nC * 256; i += 256) {
    const int cc = i >> 8, k = i & 255;
    Wf[cc][k] = Wfc[cc * 256 + k];
  }
  __syncthreads();
  for (int o = tid; o < 32 * nC; o += 256) {
    const int r = o / nC, cc = o - r * nC;
    float acc = bfc[cc];
    const float4* s4 = (const float4*)&seq[r][0];
    const float4* w4 = (const float4*)&Wf[cc][0];
#pragma unroll
    for (int q = 0; q < 64; ++q) {
      const float4 a = s4[q]; const float4 wv = w4[q];
      acc += a.x * wv.x + a.y * wv.y + a.z * wv.z + a.w * wv.w;
    }
    em[(size_t)(row0 + r) * nC + cc] = acc;
  }
}

// ---------------- fused CRF + Viterbi v2: register recurrences, no LDS in hot loops ----
__global__ __launch_bounds__(128) void crfvit_kernel(
    const float* __restrict__ em, const int* __restrict__ labels,
    const int* __restrict__ mask, const float* __restrict__ start,
    const float* __restrict__ endt, const float* __restrict__ trans,
    float* __restrict__ llh, float* __restrict__ out_path)
{
  const int b = blockIdx.x; const int tid = threadIdx.x;
  __shared__ float tr[nC * nC];
  __shared__ unsigned char bp[(nT - 1) * nC];
  __shared__ unsigned char path[nT];
  for (int i = tid; i < nC * nC; i += 128) tr[i] = trans[i];
  __syncthreads();
  const float* eb = em + (size_t)b * nT * nC;

#define MAX18(c) fmaxf(fmaxf(fmaxf(fmaxf(fmaxf(c[0], c[1]), c[2]), fmaxf(fmaxf(c[3], c[4]), c[5])),           \
                             fmaxf(fmaxf(fmaxf(c[6], c[7]), c[8]), fmaxf(fmaxf(c[9], c[10]), c[11]))),        \
                       fmaxf(fmaxf(fmaxf(c[12], c[13]), c[14]), fmaxf(fmaxf(c[15], c[16]), c[17])))

  if (tid < 64) {
    // ------- CRF wave: alpha in registers, readlane broadcast -------
    const int l = tid;
    const int lc = l < nC ? l : nC - 1;
    const int* tg = labels + (size_t)b * nT;
    const int* mk = mask + (size_t)b * nT;

    // numerator
    float np = 0.f; int cnt = 0;
    for (int t = l; t < nT; t += 64) {
      const int tag = tg[t];
      const float e = eb[(size_t)t * nC + tag];
      if (t == 0) np += start[tag] + e;
      else np += (float)mk[t] * (e + tr[tg[t - 1] * nC + tag]);
      cnt += mk[t];
    }
#pragma unroll
    for (int off = 32; off; off >>= 1) { np += __shfl_xor(np, off); cnt += __shfl_xor(cnt, off); }
    const float num = np + endt[tg[cnt - 1]];

    // tr column for this lane
    float trc[nC];
#pragma unroll
    for (int i = 0; i < nC; ++i) trc[i] = tr[i * nC + lc];

    float alpha_r = start[lc] + eb[lc];
    float eA = eb[1 * nC + lc];
    float eB = eb[2 * nC + lc];
    float eC = eb[3 * nC + lc];
    for (int tk = 0; tk < 8; ++tk) {
      const unsigned long long mb = __ballot(mk[tk * 64 + l] != 0);
      for (int tt = (tk == 0 ? 1 : 0); tt < 64; ++tt) {
        const int t = tk * 64 + tt;
        const float ecur = eA; eA = eB; eB = eC;
        const int tl = t + 3 < nT ? t + 3 : nT - 1;
        eC = eb[(size_t)tl * nC + lc];
        float cand[nC];
#pragma unroll
        for (int i = 0; i < nC; ++i) cand[i] = rlane(alpha_r, i) + trc[i];
        const float m = MAX18(cand);
        float ex[nC];
#pragma unroll
        for (int i = 0; i < nC; ++i) ex[i] = fast_exp(cand[i] - m);
        float s = 0.f;
#pragma unroll
        for (int i = 0; i < nC; ++i) s += ex[i];
        const float anew = m + fast_log(s) + ecur;
        alpha_r = ((mb >> tt) & 1) ? anew : alpha_r;
      }
    }
    const float v = (l < nC) ? (alpha_r + endt[l]) : -3.0e38f;
    float m = v;
#pragma unroll
    for (int off = 32; off; off >>= 1) m = fmaxf(m, __shfl_xor(m, off));
    float s = (l < nC) ? fast_exp(v - m) : 0.f;
#pragma unroll
    for (int off = 32; off; off >>= 1) s += __shfl_xor(s, off);
    if (l == 0) llh[b] = num - (m + fast_log(s));
  } else {
    // ------- Viterbi wave: score in registers -------
    const int l = tid - 64;
    const int lc = l < nC ? l : nC - 1;
    float trc[nC];
#pragma unroll
    for (int i = 0; i < nC; ++i) trc[i] = tr[i * nC + lc];

    float score_r = start[lc] + eb[lc];
    float eA = eb[1 * nC + lc];
    float eB = eb[2 * nC + lc];
    float eC = eb[3 * nC + lc];
    for (int t = 1; t < nT; ++t) {
      const float ecur = eA; eA = eB; eB = eC;
      const int tl = t + 3 < nT ? t + 3 : nT - 1;
      eC = eb[(size_t)tl * nC + lc];
      float cand[nC];
#pragma unroll
      for (int i = 0; i < nC; ++i) cand[i] = rlane(score_r, i) + trc[i];
      const float m = MAX18(cand);
      // first argmax: min index among cand[i]==m
      int sel[nC];
#pragma unroll
      for (int i = 0; i < nC; ++i) sel[i] = (cand[i] == m) ? i : 63;
      int arg = sel[0];
#pragma unroll
      for (int i = 1; i < nC; ++i) arg = min(arg, sel[i]);
      score_r = m + ecur;
      if (l < nC) bp[(t - 1) * nC + l] = (unsigned char)arg;
    }
    if (l == 0) {
      float mm = -3.0e38f; int last = 0;
      for (int i = 0; i < nC; ++i) {
        const float v = rlane(score_r, i) + endt[i];
        if (v > mm) { mm = v; last = i; }
      }
      path[nT - 1] = (unsigned char)last;
      int cur = last;
      for (int t = nT - 2; t >= 0; --t) { cur = bp[t * nC + cur]; path[t] = (unsigned char)cur; }
    }
    asm volatile("s_waitcnt lgkmcnt(0)" ::: "memory");
    __builtin_amdgcn_wave_barrier();
    for (int t = l; t < nT; t += 64) out_path[(size_t)b * nT + t] = (float)(path[t] + 1);
  }
#undef MAX18
}

// ---------------- loss finalize ----------------
__global__ __launch_bounds__(64) void loss_kernel(const float* __restrict__ llh, float* __restrict__ out)
{
  const int l = threadIdx.x;
  float v = llh[l];
#pragma unroll
  for (int off = 32; off; off >>= 1) v += __shfl_xor(v, off);
  if (l == 0) out[0] = -v / (float)nB;
}

extern "C" void kernel_launch(void* const* d_in, const int* in_sizes, int n_in,
                              void* d_out, int out_size, void* d_ws, size_t ws_size,
                              hipStream_t stream)
{
  const float* x      = (const float*)d_in[0];
  const int*   amask  = (const int*)d_in[1];
  const int*   labels = (const int*)d_in[2];
  const float* Wih_f  = (const float*)d_in[3];
  const float* Whh_f  = (const float*)d_in[4];
  const float* b_f    = (const float*)d_in[5];
  const float* Wih_b  = (const float*)d_in[6];
  const float* Whh_b  = (const float*)d_in[7];
  const float* b_b    = (const float*)d_in[8];
  const float* Wfc    = (const float*)d_in[9];
  const float* bfc    = (const float*)d_in[10];
  const float* start  = (const float*)d_in[11];
  const float* endt   = (const float*)d_in[12];
  const float* trans  = (const float*)d_in[13];

  float* out = (float*)d_out;
  float* ws = (float*)d_ws;
  unsigned short* preF = (unsigned short*)ws;                       // 16.7M bf16
  unsigned short* preB = preF + (size_t)nBT * nG;                   // 16.7M bf16
  unsigned short* hf   = preB + (size_t)nBT * nG;                   // 4.2M bf16
  unsigned short* hb   = hf + (size_t)nBT * nH;                     // 4.2M bf16
  float* em  = (float*)(hb + (size_t)nBT * nH);                     // 590K f32
  float* llh = em + (size_t)nBT * nC;                               // 64 f32
  unsigned short* wfb = (unsigned short*)(llh + 64);                // 393K bf16
  unsigned short* wbb = wfb + (size_t)nG * nE;                      // 393K bf16

  cvt_kernel<<<192, 256, 0, stream>>>(Wih_f, wfb, nG * nE / 8);
  cvt_kernel<<<192, 256, 0, stream>>>(Wih_b, wbb, nG * nE / 8);
  proj_kernel<<<2048, 256, 0, stream>>>(x, wfb, wbb, b_f, b_b, preF, preB);
  lstm_kernel<<<32, 512, 0, stream>>>(preF, preB, Whh_f, Whh_b, hf, hb);
  em_kernel<<<1024, 256, 0, stream>>>(hf, hb, Wfc, bfc, em);
  crfvit_kernel<<<64, 128, 0, stream>>>(em, labels, amask, start, endt, trans, llh, out);
  loss_kernel<<<1, 64, 0, stream>>>(llh, out + nBT);
}